// Round 2
// baseline (3266.156 us; speedup 1.0000x reference)
//
#include <hip/hip_runtime.h>
#include <math.h>

// B=4, S=8192, D=768, W=3D=2304
// ws layout (floats):  tw[8192) | h0f_bf16x2[3,146,496) | x3T[18,874,368)   = 84 MB total
// Per batch: gemm_wt -> x3T (2304 x 8192, row per w-channel), fused_fft (768 blocks,
// one per d; writes y2 in-place over group-0 row), gemm_out2 -> d_out.

#define LP(i) ((i) ^ ((i) >> 8))            // LDS swizzle, involution on 13-bit idx
#define BREV13(k) ((int)(__brev((unsigned)(k)) >> 19))

__device__ __forceinline__ unsigned pk_bf16x2(float a, float b) {
  unsigned ua = __float_as_uint(a); ua = (ua + 0x7FFFu + ((ua >> 16) & 1u)) >> 16;
  unsigned ub = __float_as_uint(b); ub = (ub + 0x7FFFu + ((ub >> 16) & 1u)) >> 16;
  return ua | (ub << 16);
}
__device__ __forceinline__ float bf_lo(unsigned u) { return __uint_as_float(u << 16); }
__device__ __forceinline__ float bf_hi(unsigned u) { return __uint_as_float(u & 0xFFFF0000u); }

// ---------------------------------------------------------------- twiddles exp(-2pi i k/8192)
__global__ void twfill(float2* __restrict__ tw) {
  const int k = blockIdx.x * 256 + threadIdx.x;
  if (k < 4096) {
    const double t = -2.0 * 3.14159265358979323846 * (double)k / 8192.0;
    tw[k] = make_float2((float)cos(t), (float)sin(t));
  }
}

// ---------------------------------------------------------------- h0 (8192 x 768) -> h0T (768 x 8192)
__global__ __launch_bounds__(256) void transp(const float* __restrict__ in, float* __restrict__ out) {
  __shared__ float T[64][65];
  const int d0 = blockIdx.x * 64, s0 = blockIdx.y * 64;
  const int c = threadIdx.x & 63, r0 = threadIdx.x >> 6;
#pragma unroll
  for (int i = 0; i < 16; ++i) {
    const int r = r0 + i * 4;
    T[r][c] = in[(size_t)(s0 + r) * 768 + d0 + c];
  }
  __syncthreads();
#pragma unroll
  for (int i = 0; i < 16; ++i) {
    const int r = r0 + i * 4;
    out[(size_t)(d0 + r) * 8192 + s0 + c] = T[c][r];
  }
}

// ---------------------------------------------------------------- FFT helpers (N=8192, 256 thr)
__device__ __forceinline__ void fft_dif(float* re, float* im, const float2* __restrict__ tw, int tid) {
  for (int s = 13; s >= 1; --s) {
    const int h = 1 << (s - 1);
    const int tsh = 13 - s;
#pragma unroll 4
    for (int jj = 0; jj < 16; ++jj) {
      const int j = tid + jj * 256;
      const int pos = j & (h - 1);
      const int i1 = ((j >> (s - 1)) << s) | pos;
      const int i2 = i1 + h;
      const float2 w = tw[pos << tsh];
      const int p1 = LP(i1), p2 = LP(i2);
      const float ur = re[p1], ui = im[p1];
      const float vr = re[p2], vi = im[p2];
      const float dr = ur - vr, di = ui - vi;
      re[p1] = ur + vr; im[p1] = ui + vi;
      re[p2] = dr * w.x - di * w.y;
      im[p2] = dr * w.y + di * w.x;
    }
    __syncthreads();
  }
}
__device__ __forceinline__ void fft_dit(float* re, float* im, const float2* __restrict__ tw, int tid) {
  for (int s = 1; s <= 13; ++s) {
    const int h = 1 << (s - 1);
    const int tsh = 13 - s;
#pragma unroll 4
    for (int jj = 0; jj < 16; ++jj) {
      const int j = tid + jj * 256;
      const int pos = j & (h - 1);
      const int i1 = ((j >> (s - 1)) << s) | pos;
      const int i2 = i1 + h;
      const float2 w = tw[pos << tsh];
      const int p1 = LP(i1), p2 = LP(i2);
      const float ur = re[p1], ui = im[p1];
      const float vr = re[p2], vi = im[p2];
      const float tr = vr * w.x - vi * w.y;
      const float ti = vr * w.y + vi * w.x;
      re[p1] = ur + tr; im[p1] = ui + ti;
      re[p2] = ur - tr; im[p2] = ui - ti;
    }
    __syncthreads();
  }
}

// ---------------------------------------------------------------- h0f[d,k] = bf16x2(rfft(h0T row d))
__global__ __launch_bounds__(256) void fft_h0_k(const float* __restrict__ h0T,
                                                const float2* __restrict__ tw,
                                                unsigned* __restrict__ h0f) {
  __shared__ float re[8192];
  __shared__ float im[8192];
  const int d = blockIdx.x, tid = threadIdx.x;
  const float* src = h0T + (size_t)d * 8192;
  for (int s = tid; s < 8192; s += 256) { re[LP(s)] = src[s]; im[LP(s)] = 0.f; }
  __syncthreads();
  fft_dif(re, im, tw, tid);
  for (int k = tid; k <= 4096; k += 256) {
    const int p = LP(BREV13(k));
    h0f[(size_t)d * 4097 + k] = pk_bf16x2(re[p], im[p]);
  }
}

// ---------------------------------------------------------------- fused per-(b,d) row pipeline
__global__ __launch_bounds__(256) void fused_fft(float* __restrict__ x3T,
                                                 const float2* __restrict__ tw,
                                                 const unsigned* __restrict__ h0f,
                                                 const float* __restrict__ w_short,
                                                 const float* __restrict__ b_short,
                                                 const float* __restrict__ w_cond1,
                                                 const float* __restrict__ b_cond1,
                                                 const float* __restrict__ w_cond2,
                                                 const float* __restrict__ b_cond2) {
  __shared__ float re[8192];
  __shared__ float im[8192];
  const int d = blockIdx.x, tid = threadIdx.x;
  float* g0 = x3T + (size_t)d * 8192;
  const float* g1 = x3T + (size_t)(768 + d) * 8192;
  const float* g2 = x3T + (size_t)(1536 + d) * 8192;

  const float q0 = w_cond1[d * 3], q1 = w_cond1[d * 3 + 1], q2 = w_cond1[d * 3 + 2], bc1 = b_cond1[d];
  const float t00 = w_short[d * 3], t01 = w_short[d * 3 + 1], t02 = w_short[d * 3 + 2], bs0 = b_short[d];
  const float t10 = w_short[(768 + d) * 3], t11 = w_short[(768 + d) * 3 + 1], t12 = w_short[(768 + d) * 3 + 2], bs1 = b_short[768 + d];
  const float t20 = w_short[(1536 + d) * 3], t21 = w_short[(1536 + d) * 3 + 1], t22 = w_short[(1536 + d) * 3 + 2], bs2 = b_short[1536 + d];

  // -------- phase 1: hc = conv3(g2, w_cond1) -> re ; im = 0 ; FFT
  for (int j = 0; j < 32; ++j) { const int s = tid + j * 256; re[LP(s)] = g2[s]; }
  __syncthreads();
  float tmp[32];
#pragma unroll
  for (int j = 0; j < 32; ++j) {
    const int s = tid + j * 256;
    const float a = s ? re[LP(s - 1)] : 0.f;
    const float m = re[LP(s)];
    const float z = (s < 8191) ? re[LP(s + 1)] : 0.f;
    tmp[j] = q0 * a + q1 * m + q2 * z + bc1;
  }
  __syncthreads();
#pragma unroll
  for (int j = 0; j < 32; ++j) { const int s = tid + j * 256; re[LP(s)] = tmp[j]; im[LP(s)] = 0.f; }
  __syncthreads();
  fft_dif(re, im, tw, tid);

  // -------- phase 2: hmag -> h_adapt (registers)
  float hm[17];
#pragma unroll
  for (int j = 0; j < 17; ++j) {
    const int k = tid + j * 256;
    if (k <= 4096) {
      const int p = LP(BREV13(k));
      hm[j] = sqrtf(re[p] * re[p] + im[p] * im[p]);
    }
  }
  __syncthreads();
#pragma unroll
  for (int j = 0; j < 17; ++j) { const int k = tid + j * 256; if (k <= 4096) im[LP(k)] = hm[j]; }
  __syncthreads();
  const float c0 = w_cond2[d * 3], c1 = w_cond2[d * 3 + 1], c2 = w_cond2[d * 3 + 2], bb2 = b_cond2[d];
  float ha[17];
#pragma unroll
  for (int j = 0; j < 17; ++j) {
    const int k = tid + j * 256;
    if (k <= 4096) {
      const float a = k ? im[LP(k - 1)] : 0.f;
      const float m = im[LP(k)];
      const float z = (k < 4096) ? im[LP(k + 1)] : 0.f;
      ha[j] = c0 * a + c1 * m + c2 * z + bb2;
    }
  }
  __syncthreads();

  // -------- phase 3: y = conv3(g0,ws0)*conv3(g2,ws2) -> re ; im = 0 ; FFT
  for (int j = 0; j < 32; ++j) { const int s = tid + j * 256; re[LP(s)] = g0[s]; im[LP(s)] = g2[s]; }
  __syncthreads();
#pragma unroll
  for (int j = 0; j < 32; ++j) {
    const int s = tid + j * 256;
    const float am = s ? re[LP(s - 1)] : 0.f;
    const float a  = re[LP(s)];
    const float ap = (s < 8191) ? re[LP(s + 1)] : 0.f;
    const float bm = s ? im[LP(s - 1)] : 0.f;
    const float bv = im[LP(s)];
    const float bp = (s < 8191) ? im[LP(s + 1)] : 0.f;
    const float s1v = t00 * am + t01 * a + t02 * ap + bs0;
    const float vvv = t20 * bm + t21 * bv + t22 * bp + bs2;
    tmp[j] = s1v * vvv;
  }
  __syncthreads();
#pragma unroll
  for (int j = 0; j < 32; ++j) { const int s = tid + j * 256; re[LP(s)] = tmp[j]; im[LP(s)] = 0.f; }
  __syncthreads();
  fft_dif(re, im, tw, tid);

  // -------- phase 4: G = X * (h0f + ha), conj-fill, inverse FFT
  const unsigned* H0 = h0f + (size_t)d * 4097;
#pragma unroll
  for (int j = 0; j < 17; ++j) {
    const int k = tid + j * 256;
    if (k <= 4096) {
      const int p = LP(BREV13(k));
      const float xr = re[p], xi = im[p];
      const unsigned u = H0[k];
      const float hr = bf_lo(u) + ha[j];
      const float hi = bf_hi(u);
      const float gr = xr * hr - xi * hi;
      const float gi = xr * hi + xi * hr;
      re[p] = gr; im[p] = -gi;
      if (k > 0 && k < 4096) {
        const int q = LP(BREV13(8192 - k));
        re[q] = gr; im[q] = gi;
      }
    }
  }
  __syncthreads();
  fft_dit(re, im, tw, tid);

  // -------- phase 5: y2 = re/8192 * conv3(g1,ws1) -> overwrite g0 row
  for (int j = 0; j < 32; ++j) { const int s = tid + j * 256; im[LP(s)] = g1[s]; }
  __syncthreads();
  const float inv = 1.0f / 8192.0f;
#pragma unroll
  for (int j = 0; j < 32; ++j) {
    const int s = tid + j * 256;
    const float am = s ? im[LP(s - 1)] : 0.f;
    const float a  = im[LP(s)];
    const float ap = (s < 8191) ? im[LP(s + 1)] : 0.f;
    const float s2v = t10 * am + t11 * a + t12 * ap + bs1;
    g0[s] = re[LP(s)] * inv * s2v;
  }
}

// ---------------------------------------------------------------- GEMM1: C[m][n] = sum_k w_in[m,k]*x[n,k] + b_in[m]
// M=2304, N=8192, K=768; C row-major 2304 x 8192 (= x3T)
__global__ __launch_bounds__(256) void gemm_wt(const float* __restrict__ A,
                                               const float* __restrict__ Bx,
                                               const float* __restrict__ bias,
                                               float* __restrict__ C) {
  __shared__ float As[16][132];
  __shared__ float Bs[16][132];
  const int tid = threadIdx.x;
  const int m0 = blockIdx.y * 128;
  const int n0 = blockIdx.x * 128;
  const int tr = tid >> 4, tc = tid & 15;
  float acc[8][8] = {};
  for (int k0 = 0; k0 < 768; k0 += 16) {
    __syncthreads();
#pragma unroll
    for (int i = 0; i < 2; ++i) {
      const int f = tid + 256 * i;
      const int row = f >> 2, c4 = (f & 3) << 2;
      const float4 va = *(const float4*)&A[(size_t)(m0 + row) * 768 + k0 + c4];
      As[c4 + 0][row] = va.x; As[c4 + 1][row] = va.y;
      As[c4 + 2][row] = va.z; As[c4 + 3][row] = va.w;
      const float4 vb = *(const float4*)&Bx[(size_t)(n0 + row) * 768 + k0 + c4];
      Bs[c4 + 0][row] = vb.x; Bs[c4 + 1][row] = vb.y;
      Bs[c4 + 2][row] = vb.z; Bs[c4 + 3][row] = vb.w;
    }
    __syncthreads();
#pragma unroll
    for (int kk = 0; kk < 16; ++kk) {
      float a[8], bv[8];
      *(float4*)&a[0]  = *(const float4*)&As[kk][tr * 8];
      *(float4*)&a[4]  = *(const float4*)&As[kk][tr * 8 + 4];
      *(float4*)&bv[0] = *(const float4*)&Bs[kk][tc * 8];
      *(float4*)&bv[4] = *(const float4*)&Bs[kk][tc * 8 + 4];
#pragma unroll
      for (int i = 0; i < 8; ++i)
#pragma unroll
        for (int j = 0; j < 8; ++j)
          acc[i][j] = fmaf(a[i], bv[j], acc[i][j]);
    }
  }
#pragma unroll
  for (int i = 0; i < 8; ++i) {
    const int m = m0 + tr * 8 + i;
    const float bm = bias[m];
#pragma unroll
    for (int j = 0; j < 8; ++j) {
      const int n = n0 + tc * 8 + j;
      C[(size_t)m * 8192 + n] = acc[i][j] + bm;
    }
  }
}

// ---------------------------------------------------------------- GEMM2: out[s][e] = sum_d y2[d][s]*w_out[e,d] + b_out[e]
// Y rows: x3T + d*8192 (d<768). C: 8192 x 768 (one batch of d_out).
__global__ __launch_bounds__(256) void gemm_out2(const float* __restrict__ Y,
                                                 const float* __restrict__ Bw,
                                                 const float* __restrict__ bias,
                                                 float* __restrict__ C) {
  __shared__ float As[16][132];
  __shared__ float Bs[16][132];
  const int tid = threadIdx.x;
  const int m0 = blockIdx.y * 128;   // s
  const int n0 = blockIdx.x * 128;   // e
  const int tr = tid >> 4, tc = tid & 15;
  float acc[8][8] = {};
  for (int k0 = 0; k0 < 768; k0 += 16) {
    __syncthreads();
#pragma unroll
    for (int i = 0; i < 2; ++i) {
      const int f = tid + 256 * i;
      const int kk = f >> 5;
      const int s4 = (f & 31) << 2;
      const float4 va = *(const float4*)&Y[(size_t)(k0 + kk) * 8192 + m0 + s4];
      *(float4*)&As[kk][s4] = va;
      const int row = f >> 2, c4 = (f & 3) << 2;
      const float4 vb = *(const float4*)&Bw[(size_t)(n0 + row) * 768 + k0 + c4];
      Bs[c4 + 0][row] = vb.x; Bs[c4 + 1][row] = vb.y;
      Bs[c4 + 2][row] = vb.z; Bs[c4 + 3][row] = vb.w;
    }
    __syncthreads();
#pragma unroll
    for (int kk = 0; kk < 16; ++kk) {
      float a[8], bv[8];
      *(float4*)&a[0]  = *(const float4*)&As[kk][tr * 8];
      *(float4*)&a[4]  = *(const float4*)&As[kk][tr * 8 + 4];
      *(float4*)&bv[0] = *(const float4*)&Bs[kk][tc * 8];
      *(float4*)&bv[4] = *(const float4*)&Bs[kk][tc * 8 + 4];
#pragma unroll
      for (int i = 0; i < 8; ++i)
#pragma unroll
        for (int j = 0; j < 8; ++j)
          acc[i][j] = fmaf(a[i], bv[j], acc[i][j]);
    }
  }
#pragma unroll
  for (int i = 0; i < 8; ++i) {
    const int m = m0 + tr * 8 + i;
#pragma unroll
    for (int j = 0; j < 8; ++j) {
      const int n = n0 + tc * 8 + j;
      C[(size_t)m * 768 + n] = acc[i][j] + bias[n];
    }
  }
}

// ---------------------------------------------------------------- launch
extern "C" void kernel_launch(void* const* d_in, const int* in_sizes, int n_in,
                              void* d_out, int out_size, void* d_ws, size_t ws_size,
                              hipStream_t stream) {
  (void)in_sizes; (void)n_in; (void)out_size; (void)ws_size;
  const float* x       = (const float*)d_in[0];
  const float* w_in    = (const float*)d_in[1];
  const float* b_in    = (const float*)d_in[2];
  const float* w_short = (const float*)d_in[3];
  const float* b_short = (const float*)d_in[4];
  const float* w_cond1 = (const float*)d_in[5];
  const float* b_cond1 = (const float*)d_in[6];
  const float* w_cond2 = (const float*)d_in[7];
  const float* b_cond2 = (const float*)d_in[8];
  const float* h0      = (const float*)d_in[9];
  const float* w_out   = (const float*)d_in[10];
  const float* b_out   = (const float*)d_in[11];

  float*    ws  = (float*)d_ws;
  float2*   tw  = (float2*)ws;                       // 8,192 floats
  unsigned* h0f = (unsigned*)(ws + 8192);            // 3,146,496 u32 (bf16x2)
  float*    x3T = ws + 8192 + 3146496;               // 18,874,368 floats
  float*    h0T = x3T;                                // transient staging

  twfill<<<16, 256, 0, stream>>>(tw);
  transp<<<dim3(12, 128), 256, 0, stream>>>(h0, h0T);
  fft_h0_k<<<768, 256, 0, stream>>>(h0T, tw, h0f);

  for (int b = 0; b < 4; ++b) {
    gemm_wt<<<dim3(64, 18), 256, 0, stream>>>(w_in, x + (size_t)b * 8192 * 768, b_in, x3T);
    fused_fft<<<768, 256, 0, stream>>>(x3T, tw, h0f,
                                       w_short, b_short, w_cond1, b_cond1, w_cond2, b_cond2);
    gemm_out2<<<dim3(6, 64), 256, 0, stream>>>(x3T, w_out, b_out,
                                               (float*)d_out + (size_t)b * 8192 * 768);
  }
}

// Round 3
// 1634.763 us; speedup vs baseline: 1.9979x; 1.9979x over previous
//
#include <hip/hip_runtime.h>
#include <math.h>

// B=4, S=8192, D=768, W=3D=2304
// ws (floats): tw[8192] | h0f f32x2 [6292992] | xb bf16 [3145728 slots] |
//              w_inb [884736] | w_outb [294912] | x3Tb bf16 [9437184 slots]
//              (h0T fp32 transient in x3Tb region; y2b bf16 aliases g1/g2 region)
// Total 20,063,744 floats = 80.3 MB

typedef unsigned short u16;
typedef short s16x8 __attribute__((ext_vector_type(8)));
typedef float f32x4 __attribute__((ext_vector_type(4)));
typedef u16 u16x8 __attribute__((ext_vector_type(8)));

#define LP(i) ((i) ^ ((i) >> 8))            // FFT LDS swizzle, involution on 13-bit idx
#define BREV13(k) ((int)(__brev((unsigned)(k)) >> 19))

__device__ __forceinline__ u16 f2bf(float f) {
  unsigned u = __float_as_uint(f);
  u = (u + 0x7FFFu + ((u >> 16) & 1u)) >> 16;
  return (u16)u;
}
__device__ __forceinline__ float bf2f(u16 u) { return __uint_as_float(((unsigned)u) << 16); }

__device__ __forceinline__ void glds16(const void* g, void* l) {
  __builtin_amdgcn_global_load_lds((const __attribute__((address_space(1))) unsigned*)g,
                                   (__attribute__((address_space(3))) unsigned*)l, 16, 0, 0);
}

// ---------------------------------------------------------------- float -> bf16 (n8 = n/8)
__global__ __launch_bounds__(256) void cvt_bf16(const float* __restrict__ in,
                                                u16* __restrict__ out, int n8) {
  const int i = blockIdx.x * 256 + threadIdx.x;
  if (i < n8) {
    const float4 a = ((const float4*)in)[i * 2];
    const float4 b = ((const float4*)in)[i * 2 + 1];
    u16x8 r;
    r[0] = f2bf(a.x); r[1] = f2bf(a.y); r[2] = f2bf(a.z); r[3] = f2bf(a.w);
    r[4] = f2bf(b.x); r[5] = f2bf(b.y); r[6] = f2bf(b.z); r[7] = f2bf(b.w);
    ((u16x8*)out)[i] = r;
  }
}

// ---------------------------------------------------------------- MFMA GEMM: C[m][n] = sum_k A[m][k]*B[n][k] (+bias)
// 128x128 tile, BK=32, 4 waves (2x2), global_load_lds w16, line-swizzled LDS.
// BIAS_M=1: bias[m], bf16 output. BIAS_M=0: bias[n], fp32 output.
template <int BIAS_M>
__global__ __launch_bounds__(256) void gemm_bt(const u16* __restrict__ A,
                                               const u16* __restrict__ B,
                                               const float* __restrict__ bias,
                                               void* __restrict__ Cout,
                                               int N, int K) {
  __shared__ __align__(16) u16 As[4096];
  __shared__ __align__(16) u16 Bs[4096];
  const int tid = threadIdx.x;
  const int w = tid >> 6, l = tid & 63;
  const int m0 = blockIdx.y * 128, n0 = blockIdx.x * 128;
  const int wr = w >> 1, wc = w & 1;
  const int lr = l & 15, kc = l >> 4;

  // staging: physical 16B-chunk p -> line=p>>3, slot_log=(p&7)^(line&7),
  //          logical row r = line*2 + (slot_log>>2), k-chunk = slot_log&3
  const int p0 = w * 64 + l;
  const int p1 = p0 + 256;
  const int sl0 = (p0 & 7) ^ ((p0 >> 3) & 7);
  const int sl1 = (p1 & 7) ^ ((p1 >> 3) & 7);
  const int r0 = ((p0 >> 3) << 1) | (sl0 >> 2), ka = (sl0 & 3) << 3;
  const int r1 = ((p1 >> 3) << 1) | (sl1 >> 2), kb = (sl1 & 3) << 3;
  const u16* gA0 = A + (size_t)(m0 + r0) * K + ka;
  const u16* gA1 = A + (size_t)(m0 + r1) * K + kb;
  const u16* gB0 = B + (size_t)(n0 + r0) * K + ka;
  const u16* gB1 = B + (size_t)(n0 + r1) * K + kb;
  u16* lA0 = &As[(size_t)w * 512];
  u16* lA1 = &As[(size_t)(4 + w) * 512];
  u16* lB0 = &Bs[(size_t)w * 512];
  u16* lB1 = &Bs[(size_t)(4 + w) * 512];

  f32x4 acc[4][4] = {};

  for (int k0 = 0; k0 < K; k0 += 32) {
    glds16(gA0 + k0, lA0);
    glds16(gA1 + k0, lA1);
    glds16(gB0 + k0, lB0);
    glds16(gB1 + k0, lB1);
    __syncthreads();
    s16x8 af[4], bfr[4];
#pragma unroll
    for (int mi = 0; mi < 4; ++mi) {
      const int row = wr * 64 + mi * 16 + lr;
      const int slot = (((lr & 1) << 2) | kc) ^ ((lr >> 1) & 7);
      af[mi] = *(const s16x8*)&As[(row >> 1) * 64 + slot * 8];
    }
#pragma unroll
    for (int ni = 0; ni < 4; ++ni) {
      const int row = wc * 64 + ni * 16 + lr;
      const int slot = (((lr & 1) << 2) | kc) ^ ((lr >> 1) & 7);
      bfr[ni] = *(const s16x8*)&Bs[(row >> 1) * 64 + slot * 8];
    }
#pragma unroll
    for (int mi = 0; mi < 4; ++mi)
#pragma unroll
      for (int ni = 0; ni < 4; ++ni)
        acc[mi][ni] = __builtin_amdgcn_mfma_f32_16x16x32_bf16(af[mi], bfr[ni], acc[mi][ni], 0, 0, 0);
    __syncthreads();
  }

  const int rbase = m0 + wr * 64 + (kc << 2);
  const int cbase = n0 + wc * 64 + lr;
#pragma unroll
  for (int mi = 0; mi < 4; ++mi)
#pragma unroll
    for (int j = 0; j < 4; ++j) {
      const int row = rbase + mi * 16 + j;
      const float bm = BIAS_M ? bias[row] : 0.f;
#pragma unroll
      for (int ni = 0; ni < 4; ++ni) {
        const int col = cbase + ni * 16;
        const float v = acc[mi][ni][j] + (BIAS_M ? bm : bias[col]);
        if (BIAS_M) ((u16*)Cout)[(size_t)row * N + col] = f2bf(v);
        else        ((float*)Cout)[(size_t)row * N + col] = v;
      }
    }
}

// ---------------------------------------------------------------- twiddles exp(-2pi i k/8192)
__global__ void twfill(float2* __restrict__ tw) {
  const int k = blockIdx.x * 256 + threadIdx.x;
  if (k < 4096) {
    const double t = -2.0 * 3.14159265358979323846 * (double)k / 8192.0;
    tw[k] = make_float2((float)cos(t), (float)sin(t));
  }
}

// ---------------------------------------------------------------- h0 (8192 x 768) -> h0T (768 x 8192) fp32
__global__ __launch_bounds__(256) void transp(const float* __restrict__ in, float* __restrict__ out) {
  __shared__ float T[64][65];
  const int d0 = blockIdx.x * 64, s0 = blockIdx.y * 64;
  const int c = threadIdx.x & 63, r0 = threadIdx.x >> 6;
#pragma unroll
  for (int i = 0; i < 16; ++i) {
    const int r = r0 + i * 4;
    T[r][c] = in[(size_t)(s0 + r) * 768 + d0 + c];
  }
  __syncthreads();
#pragma unroll
  for (int i = 0; i < 16; ++i) {
    const int r = r0 + i * 4;
    out[(size_t)(d0 + r) * 8192 + s0 + c] = T[c][r];
  }
}

// ---------------------------------------------------------------- FFT helpers (N=8192, 256 thr)
__device__ __forceinline__ void fft_dif(float* re, float* im, const float2* __restrict__ tw, int tid) {
  for (int s = 13; s >= 1; --s) {
    const int h = 1 << (s - 1);
    const int tsh = 13 - s;
#pragma unroll 4
    for (int jj = 0; jj < 16; ++jj) {
      const int j = tid + jj * 256;
      const int pos = j & (h - 1);
      const int i1 = ((j >> (s - 1)) << s) | pos;
      const int i2 = i1 + h;
      const float2 w = tw[pos << tsh];
      const int p1 = LP(i1), p2 = LP(i2);
      const float ur = re[p1], ui = im[p1];
      const float vr = re[p2], vi = im[p2];
      const float dr = ur - vr, di = ui - vi;
      re[p1] = ur + vr; im[p1] = ui + vi;
      re[p2] = dr * w.x - di * w.y;
      im[p2] = dr * w.y + di * w.x;
    }
    __syncthreads();
  }
}
__device__ __forceinline__ void fft_dit(float* re, float* im, const float2* __restrict__ tw, int tid) {
  for (int s = 1; s <= 13; ++s) {
    const int h = 1 << (s - 1);
    const int tsh = 13 - s;
#pragma unroll 4
    for (int jj = 0; jj < 16; ++jj) {
      const int j = tid + jj * 256;
      const int pos = j & (h - 1);
      const int i1 = ((j >> (s - 1)) << s) | pos;
      const int i2 = i1 + h;
      const float2 w = tw[pos << tsh];
      const int p1 = LP(i1), p2 = LP(i2);
      const float ur = re[p1], ui = im[p1];
      const float vr = re[p2], vi = im[p2];
      const float tr = vr * w.x - vi * w.y;
      const float ti = vr * w.y + vi * w.x;
      re[p1] = ur + tr; im[p1] = ui + ti;
      re[p2] = ur - tr; im[p2] = ui - ti;
    }
    __syncthreads();
  }
}

// ---------------------------------------------------------------- h0f[d,k] = rfft(h0T row d)  (fp32)
__global__ __launch_bounds__(256) void fft_h0_k(const float* __restrict__ h0T,
                                                const float2* __restrict__ tw,
                                                float2* __restrict__ h0f) {
  __shared__ float re[8192];
  __shared__ float im[8192];
  const int d = blockIdx.x, tid = threadIdx.x;
  const float* src = h0T + (size_t)d * 8192;
  for (int s = tid; s < 8192; s += 256) { re[LP(s)] = src[s]; im[LP(s)] = 0.f; }
  __syncthreads();
  fft_dif(re, im, tw, tid);
  for (int k = tid; k <= 4096; k += 256) {
    const int p = LP(BREV13(k));
    h0f[(size_t)d * 4097 + k] = make_float2(re[p], im[p]);
  }
}

// ---------------------------------------------------------------- fused per-(b,d) row pipeline (bf16 I/O)
__global__ __launch_bounds__(256) void fused_fft(u16* __restrict__ x3T,
                                                 const float2* __restrict__ tw,
                                                 const float2* __restrict__ h0f,
                                                 const float* __restrict__ w_short,
                                                 const float* __restrict__ b_short,
                                                 const float* __restrict__ w_cond1,
                                                 const float* __restrict__ b_cond1,
                                                 const float* __restrict__ w_cond2,
                                                 const float* __restrict__ b_cond2) {
  __shared__ float re[8192];
  __shared__ float im[8192];
  const int d = blockIdx.x, tid = threadIdx.x;
  u16* g0 = x3T + (size_t)d * 8192;
  const u16* g1 = x3T + (size_t)(768 + d) * 8192;
  const u16* g2 = x3T + (size_t)(1536 + d) * 8192;

  const float q0 = w_cond1[d * 3], q1 = w_cond1[d * 3 + 1], q2 = w_cond1[d * 3 + 2], bc1 = b_cond1[d];
  const float t00 = w_short[d * 3], t01 = w_short[d * 3 + 1], t02 = w_short[d * 3 + 2], bs0 = b_short[d];
  const float t10 = w_short[(768 + d) * 3], t11 = w_short[(768 + d) * 3 + 1], t12 = w_short[(768 + d) * 3 + 2], bs1 = b_short[768 + d];
  const float t20 = w_short[(1536 + d) * 3], t21 = w_short[(1536 + d) * 3 + 1], t22 = w_short[(1536 + d) * 3 + 2], bs2 = b_short[1536 + d];

  // -------- phase 1: hc = conv3(g2, w_cond1) -> re ; im = 0 ; FFT
  for (int j = 0; j < 32; ++j) { const int s = tid + j * 256; re[LP(s)] = bf2f(g2[s]); }
  __syncthreads();
  float tmp[32];
#pragma unroll
  for (int j = 0; j < 32; ++j) {
    const int s = tid + j * 256;
    const float a = s ? re[LP(s - 1)] : 0.f;
    const float m = re[LP(s)];
    const float z = (s < 8191) ? re[LP(s + 1)] : 0.f;
    tmp[j] = q0 * a + q1 * m + q2 * z + bc1;
  }
  __syncthreads();
#pragma unroll
  for (int j = 0; j < 32; ++j) { const int s = tid + j * 256; re[LP(s)] = tmp[j]; im[LP(s)] = 0.f; }
  __syncthreads();
  fft_dif(re, im, tw, tid);

  // -------- phase 2: hmag -> h_adapt (registers)
  float hm[17];
#pragma unroll
  for (int j = 0; j < 17; ++j) {
    const int k = tid + j * 256;
    if (k <= 4096) {
      const int p = LP(BREV13(k));
      hm[j] = sqrtf(re[p] * re[p] + im[p] * im[p]);
    }
  }
  __syncthreads();
#pragma unroll
  for (int j = 0; j < 17; ++j) { const int k = tid + j * 256; if (k <= 4096) im[LP(k)] = hm[j]; }
  __syncthreads();
  const float c0 = w_cond2[d * 3], c1 = w_cond2[d * 3 + 1], c2 = w_cond2[d * 3 + 2], bb2 = b_cond2[d];
  float ha[17];
#pragma unroll
  for (int j = 0; j < 17; ++j) {
    const int k = tid + j * 256;
    if (k <= 4096) {
      const float a = k ? im[LP(k - 1)] : 0.f;
      const float m = im[LP(k)];
      const float z = (k < 4096) ? im[LP(k + 1)] : 0.f;
      ha[j] = c0 * a + c1 * m + c2 * z + bb2;
    }
  }
  __syncthreads();

  // -------- phase 3: y = conv3(g0,ws0)*conv3(g2,ws2) -> re ; im = 0 ; FFT
  for (int j = 0; j < 32; ++j) { const int s = tid + j * 256; re[LP(s)] = bf2f(g0[s]); im[LP(s)] = bf2f(g2[s]); }
  __syncthreads();
#pragma unroll
  for (int j = 0; j < 32; ++j) {
    const int s = tid + j * 256;
    const float am = s ? re[LP(s - 1)] : 0.f;
    const float a  = re[LP(s)];
    const float ap = (s < 8191) ? re[LP(s + 1)] : 0.f;
    const float bm = s ? im[LP(s - 1)] : 0.f;
    const float bv = im[LP(s)];
    const float bp = (s < 8191) ? im[LP(s + 1)] : 0.f;
    const float s1v = t00 * am + t01 * a + t02 * ap + bs0;
    const float vvv = t20 * bm + t21 * bv + t22 * bp + bs2;
    tmp[j] = s1v * vvv;
  }
  __syncthreads();
#pragma unroll
  for (int j = 0; j < 32; ++j) { const int s = tid + j * 256; re[LP(s)] = tmp[j]; im[LP(s)] = 0.f; }
  __syncthreads();
  fft_dif(re, im, tw, tid);

  // -------- phase 4: G = X * (h0f + ha), conj-fill, inverse FFT
  const float2* H0 = h0f + (size_t)d * 4097;
#pragma unroll
  for (int j = 0; j < 17; ++j) {
    const int k = tid + j * 256;
    if (k <= 4096) {
      const int p = LP(BREV13(k));
      const float xr = re[p], xi = im[p];
      const float2 h = H0[k];
      const float hr = h.x + ha[j];
      const float hi = h.y;
      const float gr = xr * hr - xi * hi;
      const float gi = xr * hi + xi * hr;
      re[p] = gr; im[p] = -gi;
      if (k > 0 && k < 4096) {
        const int q = LP(BREV13(8192 - k));
        re[q] = gr; im[q] = gi;
      }
    }
  }
  __syncthreads();
  fft_dit(re, im, tw, tid);

  // -------- phase 5: y2 = re/8192 * conv3(g1,ws1) -> overwrite g0 row (bf16)
  for (int j = 0; j < 32; ++j) { const int s = tid + j * 256; im[LP(s)] = bf2f(g1[s]); }
  __syncthreads();
  const float inv = 1.0f / 8192.0f;
#pragma unroll
  for (int j = 0; j < 32; ++j) {
    const int s = tid + j * 256;
    const float am = s ? im[LP(s - 1)] : 0.f;
    const float a  = im[LP(s)];
    const float ap = (s < 8191) ? im[LP(s + 1)] : 0.f;
    const float s2v = t10 * am + t11 * a + t12 * ap + bs1;
    g0[s] = f2bf(re[LP(s)] * inv * s2v);
  }
}

// ---------------------------------------------------------------- y2 rows (768 x 8192) -> y2b (8192 x 768) bf16
__global__ __launch_bounds__(256) void y2t(const u16* __restrict__ y2rows, u16* __restrict__ y2b) {
  __shared__ u16 T[64][65];
  const int d0 = blockIdx.x * 64, s0 = blockIdx.y * 64;
  const int c = threadIdx.x & 63, r0 = threadIdx.x >> 6;
#pragma unroll
  for (int i = 0; i < 16; ++i) {
    const int r = r0 + i * 4;
    T[r][c] = y2rows[(size_t)(d0 + r) * 8192 + s0 + c];
  }
  __syncthreads();
#pragma unroll
  for (int i = 0; i < 16; ++i) {
    const int r = r0 + i * 4;
    y2b[(size_t)(s0 + r) * 768 + d0 + c] = T[c][r];
  }
}

// ---------------------------------------------------------------- launch
extern "C" void kernel_launch(void* const* d_in, const int* in_sizes, int n_in,
                              void* d_out, int out_size, void* d_ws, size_t ws_size,
                              hipStream_t stream) {
  (void)in_sizes; (void)n_in; (void)out_size; (void)ws_size;
  const float* x       = (const float*)d_in[0];
  const float* w_in    = (const float*)d_in[1];
  const float* b_in    = (const float*)d_in[2];
  const float* w_short = (const float*)d_in[3];
  const float* b_short = (const float*)d_in[4];
  const float* w_cond1 = (const float*)d_in[5];
  const float* b_cond1 = (const float*)d_in[6];
  const float* w_cond2 = (const float*)d_in[7];
  const float* b_cond2 = (const float*)d_in[8];
  const float* h0      = (const float*)d_in[9];
  const float* w_out   = (const float*)d_in[10];
  const float* b_out   = (const float*)d_in[11];

  float* ws = (float*)d_ws;
  float2* tw     = (float2*)ws;                          // 8192 floats
  float2* h0f    = (float2*)(ws + 8192);                 // 6,292,992 floats
  u16*    xb     = (u16*)(ws + 6301184);                 // 3,145,728 slots
  u16*    w_inb  = (u16*)(ws + 9446912);                 // 884,736 slots
  u16*    w_outb = (u16*)(ws + 10331648);                // 294,912 slots
  u16*    x3Tb   = (u16*)(ws + 10626560);                // 9,437,184 slots
  float*  h0T    = (float*)x3Tb;                         // transient
  u16*    y2b    = x3Tb + 6291456;                       // aliases g1/g2 after fused_fft

  twfill<<<16, 256, 0, stream>>>(tw);
  transp<<<dim3(12, 128), 256, 0, stream>>>(h0, h0T);
  fft_h0_k<<<768, 256, 0, stream>>>(h0T, tw, h0f);
  cvt_bf16<<<864, 256, 0, stream>>>(w_in, w_inb, 221184);
  cvt_bf16<<<288, 256, 0, stream>>>(w_out, w_outb, 73728);

  for (int b = 0; b < 4; ++b) {
    cvt_bf16<<<3072, 256, 0, stream>>>(x + (size_t)b * 6291456, xb, 786432);
    gemm_bt<1><<<dim3(64, 18), 256, 0, stream>>>(w_inb, xb, b_in, x3Tb, 8192, 768);
    fused_fft<<<768, 256, 0, stream>>>(x3Tb, tw, h0f,
                                       w_short, b_short, w_cond1, b_cond1, w_cond2, b_cond2);
    y2t<<<dim3(12, 128), 256, 0, stream>>>(x3Tb, y2b);
    gemm_bt<0><<<dim3(6, 64), 256, 0, stream>>>(y2b, w_outb, b_out,
                                                (float*)d_out + (size_t)b * 6291456, 768, 768);
  }
}

// Round 5
// 869.430 us; speedup vs baseline: 3.7567x; 1.8803x over previous
//
#include <hip/hip_runtime.h>
#include <math.h>

// B=4, S=8192, D=768, W=3D=2304
// ws (floats): tw f32x2[8192]            [0       .. 16384)
//              h0f f32x2[768*4097]       [16384   .. 6309376)
//              xb   bf16 6291456 u16     [6309376 .. 9455104)
//              w_inb bf16 1769472 u16    [9455104 .. 10339840)
//              w_outb bf16 589824 u16    [10339840.. 10634752)
//              x3Tb bf16 18874368 u16    [10634752.. 20071936)   total 80.3 MB
// h0T (fp32, 6291456 floats, transient) aliases xb.. regions before they're written.
// y2b (bf16) aliases x3Tb's g1/g2 rows after fused_fft.

typedef unsigned short u16;
typedef short s16x8 __attribute__((ext_vector_type(8)));
typedef float f32x4 __attribute__((ext_vector_type(4)));
typedef u16 u16x8 __attribute__((ext_vector_type(8)));

#define LP(i) ((i) ^ ((i) >> 8))            // LDS swizzle, involution, keeps 12/13-bit ranges
#define BREV13(k) ((int)(__brev((unsigned)(k)) >> 19))
#define BREV12(k) ((int)(__brev((unsigned)(k)) >> 20))
#define CMUL(rr, ri, xr, xi, wr, wi) { rr = (xr)*(wr) - (xi)*(wi); ri = (xr)*(wi) + (xi)*(wr); }

__device__ __forceinline__ u16 f2bf(float f) {
  unsigned u = __float_as_uint(f);
  u = (u + 0x7FFFu + ((u >> 16) & 1u)) >> 16;
  return (u16)u;
}
__device__ __forceinline__ float bf2f(u16 u) { return __uint_as_float(((unsigned)u) << 16); }

__device__ __forceinline__ void glds16(const void* g, void* l) {
  __builtin_amdgcn_global_load_lds((const __attribute__((address_space(1))) unsigned*)g,
                                   (__attribute__((address_space(3))) unsigned*)l, 16, 0, 0);
}

// ---------------------------------------------------------------- float -> bf16
__global__ __launch_bounds__(256) void cvt_bf16(const float* __restrict__ in,
                                                u16* __restrict__ out, int n8) {
  const int i = blockIdx.x * 256 + threadIdx.x;
  if (i < n8) {
    const float4 a = ((const float4*)in)[i * 2];
    const float4 b = ((const float4*)in)[i * 2 + 1];
    u16x8 r;
    r[0] = f2bf(a.x); r[1] = f2bf(a.y); r[2] = f2bf(a.z); r[3] = f2bf(a.w);
    r[4] = f2bf(b.x); r[5] = f2bf(b.y); r[6] = f2bf(b.z); r[7] = f2bf(b.w);
    ((u16x8*)out)[i] = r;
  }
}

// ---------------------------------------------------------------- MFMA GEMM
template <int BIAS_M>
__global__ __launch_bounds__(256) void gemm_bt(const u16* __restrict__ A,
                                               const u16* __restrict__ B,
                                               const float* __restrict__ bias,
                                               void* __restrict__ Cout,
                                               int N, int K) {
  __shared__ __align__(16) u16 As[4096];
  __shared__ __align__(16) u16 Bs[4096];
  const int tid = threadIdx.x;
  const int w = tid >> 6, l = tid & 63;
  const int m0 = blockIdx.y * 128, n0 = blockIdx.x * 128;
  const int wr = w >> 1, wc = w & 1;
  const int lr = l & 15, kc = l >> 4;

  const int p0 = w * 64 + l;
  const int p1 = p0 + 256;
  const int sl0 = (p0 & 7) ^ ((p0 >> 3) & 7);
  const int sl1 = (p1 & 7) ^ ((p1 >> 3) & 7);
  const int r0 = ((p0 >> 3) << 1) | (sl0 >> 2), ka = (sl0 & 3) << 3;
  const int r1 = ((p1 >> 3) << 1) | (sl1 >> 2), kb = (sl1 & 3) << 3;
  const u16* gA0 = A + (size_t)(m0 + r0) * K + ka;
  const u16* gA1 = A + (size_t)(m0 + r1) * K + kb;
  const u16* gB0 = B + (size_t)(n0 + r0) * K + ka;
  const u16* gB1 = B + (size_t)(n0 + r1) * K + kb;
  u16* lA0 = &As[(size_t)w * 512];
  u16* lA1 = &As[(size_t)(4 + w) * 512];
  u16* lB0 = &Bs[(size_t)w * 512];
  u16* lB1 = &Bs[(size_t)(4 + w) * 512];

  f32x4 acc[4][4] = {};

  for (int k0 = 0; k0 < K; k0 += 32) {
    glds16(gA0 + k0, lA0);
    glds16(gA1 + k0, lA1);
    glds16(gB0 + k0, lB0);
    glds16(gB1 + k0, lB1);
    __syncthreads();
    s16x8 af[4], bfr[4];
#pragma unroll
    for (int mi = 0; mi < 4; ++mi) {
      const int row = wr * 64 + mi * 16 + lr;
      const int slot = (((lr & 1) << 2) | kc) ^ ((lr >> 1) & 7);
      af[mi] = *(const s16x8*)&As[(row >> 1) * 64 + slot * 8];
    }
#pragma unroll
    for (int ni = 0; ni < 4; ++ni) {
      const int row = wc * 64 + ni * 16 + lr;
      const int slot = (((lr & 1) << 2) | kc) ^ ((lr >> 1) & 7);
      bfr[ni] = *(const s16x8*)&Bs[(row >> 1) * 64 + slot * 8];
    }
#pragma unroll
    for (int mi = 0; mi < 4; ++mi)
#pragma unroll
      for (int ni = 0; ni < 4; ++ni)
        acc[mi][ni] = __builtin_amdgcn_mfma_f32_16x16x32_bf16(af[mi], bfr[ni], acc[mi][ni], 0, 0, 0);
    __syncthreads();
  }

  const int rbase = m0 + wr * 64 + (kc << 2);
  const int cbase = n0 + wc * 64 + lr;
#pragma unroll
  for (int mi = 0; mi < 4; ++mi)
#pragma unroll
    for (int j = 0; j < 4; ++j) {
      const int row = rbase + mi * 16 + j;
      const float bm = BIAS_M ? bias[row] : 0.f;
#pragma unroll
      for (int ni = 0; ni < 4; ++ni) {
        const int col = cbase + ni * 16;
        const float v = acc[mi][ni][j] + (BIAS_M ? bm : bias[col]);
        if (BIAS_M) ((u16*)Cout)[(size_t)row * N + col] = f2bf(v);
        else        ((float*)Cout)[(size_t)row * N + col] = v;
      }
    }
}

// ---------------------------------------------------------------- twiddles exp(-2pi i k/8192), k<8192
__global__ void twfill(float2* __restrict__ tw) {
  const int k = blockIdx.x * 256 + threadIdx.x;
  if (k < 8192) {
    const double t = -2.0 * 3.14159265358979323846 * (double)k / 8192.0;
    tw[k] = make_float2((float)cos(t), (float)sin(t));
  }
}

// ---------------------------------------------------------------- h0 (8192 x 768) -> h0T (768 x 8192) fp32
__global__ __launch_bounds__(256) void transp(const float* __restrict__ in, float* __restrict__ out) {
  __shared__ float T[64][65];
  const int d0 = blockIdx.x * 64, s0 = blockIdx.y * 64;
  const int c = threadIdx.x & 63, r0 = threadIdx.x >> 6;
#pragma unroll
  for (int i = 0; i < 16; ++i) {
    const int r = r0 + i * 4;
    T[r][c] = in[(size_t)(s0 + r) * 768 + d0 + c];
  }
  __syncthreads();
#pragma unroll
  for (int i = 0; i < 16; ++i) {
    const int r = r0 + i * 4;
    out[(size_t)(d0 + r) * 8192 + s0 + c] = T[c][r];
  }
}

// ---------------------------------------------------------------- forward 8192 FFT: 6 radix-4 + 1 radix-2
// Exact fusion of the verified radix-2 DIF network -> output layout = 13-bit bit-reversal.
__device__ __forceinline__ void fwd8192(float* re, float* im, const float2* __restrict__ tw, int tid) {
  for (int s = 13; s >= 3; s -= 2) {
    const int h = 1 << (s - 2);
    const int e = 13 - s;
#pragma unroll 2
    for (int t = 0; t < 8; ++t) {
      const int g = tid + t * 256;
      const int b = g >> (s - 2);
      const int j = g & (h - 1);
      const int base = (b << s) | j;
      const int p0 = LP(base), p1 = LP(base + h), p2 = LP(base + 2 * h), p3 = LP(base + 3 * h);
      const float ar = re[p0], ai = im[p0];
      const float br = re[p1], bi = im[p1];
      const float cr = re[p2], ci = im[p2];
      const float dr = re[p3], di = im[p3];
      const float2 w1 = tw[j << e];
      const float2 w2 = tw[(2 * j) << e];
      const float2 w3 = tw[(3 * j) << e];
      const float apr = ar + cr, api = ai + ci, amr = ar - cr, ami = ai - ci;
      const float bpr = br + dr, bpi = bi + di, bmr = br - dr, bmi = bi - di;
      re[p0] = apr + bpr; im[p0] = api + bpi;
      const float x1r = apr - bpr, x1i = api - bpi;
      CMUL(re[p1], im[p1], x1r, x1i, w2.x, w2.y);
      const float x2r = amr + bmi, x2i = ami - bmr;      // (a-c) - i(b-d)
      CMUL(re[p2], im[p2], x2r, x2i, w1.x, w1.y);
      const float x3r = amr - bmi, x3i = ami + bmr;      // (a-c) + i(b-d)
      CMUL(re[p3], im[p3], x3r, x3i, w3.x, w3.y);
    }
    __syncthreads();
  }
  // final radix-2, stride 1, twiddle 1
#pragma unroll 4
  for (int t = 0; t < 16; ++t) {
    const int g = tid + t * 256;
    const int p = LP(2 * g), q = LP(2 * g + 1);
    const float ur = re[p], ui = im[p];
    const float vr = re[q], vi = im[q];
    re[p] = ur + vr; im[p] = ui + vi;
    re[q] = ur - vr; im[q] = ui - vi;
  }
  __syncthreads();
}

// ---------------------------------------------------------------- inverse-core 4096 FFT (forward twiddles; caller conjugates)
// 6 pure radix-4 DIT stages; input at 12-bit bit-reversed slots, output natural.
__device__ __forceinline__ void inv4096(float* re, float* im, const float2* __restrict__ tw, int tid) {
  for (int s = 1; s <= 11; s += 2) {
    const int h = 1 << (s - 1);
    const int e = 12 - s;
#pragma unroll 2
    for (int t = 0; t < 4; ++t) {
      const int g = tid + t * 256;
      const int b = g >> (s - 1);
      const int j = g & (h - 1);
      const int base = (b << (s + 1)) | j;
      const int p0 = LP(base), p1 = LP(base + h), p2 = LP(base + 2 * h), p3 = LP(base + 3 * h);
      const float ar = re[p0], ai = im[p0];
      const float br = re[p1], bi = im[p1];
      const float cr = re[p2], ci = im[p2];
      const float dr = re[p3], di = im[p3];
      const float2 w1 = tw[j << e];
      const float2 w2 = tw[(2 * j) << e];
      float vbr, vbi, vdr, vdi;
      CMUL(vbr, vbi, br, bi, w2.x, w2.y);
      CMUL(vdr, vdi, dr, di, w2.x, w2.y);
      const float a1r = ar + vbr, a1i = ai + vbi;
      const float b1r = ar - vbr, b1i = ai - vbi;
      const float c1r = cr + vdr, c1i = ci + vdi;
      const float d1r = cr - vdr, d1i = ci - vdi;
      float t1r, t1i, ur, ui;
      CMUL(t1r, t1i, c1r, c1i, w1.x, w1.y);
      CMUL(ur, ui, d1r, d1i, w1.y, -w1.x);               // x * (-i*w1)
      re[p0] = a1r + t1r; im[p0] = a1i + t1i;
      re[p2] = a1r - t1r; im[p2] = a1i - t1i;
      re[p1] = b1r + ur;  im[p1] = b1i + ui;
      re[p3] = b1r - ur;  im[p3] = b1i - ui;
    }
    __syncthreads();
  }
}

// ---------------------------------------------------------------- h0f[d,k] = rfft(h0T row d) (fp32)
__global__ __launch_bounds__(256) void fft_h0_k(const float* __restrict__ h0T,
                                                const float2* __restrict__ tw,
                                                float2* __restrict__ h0f) {
  __shared__ float re[8192];
  __shared__ float im[8192];
  const int d = blockIdx.x, tid = threadIdx.x;
  const float* src = h0T + (size_t)d * 8192;
  for (int s = tid; s < 8192; s += 256) { re[LP(s)] = src[s]; im[LP(s)] = 0.f; }
  __syncthreads();
  fwd8192(re, im, tw, tid);
  for (int k = tid; k <= 4096; k += 256) {
    const int p = LP(BREV13(k));
    h0f[(size_t)d * 4097 + k] = make_float2(re[p], im[p]);
  }
}

// ---------------------------------------------------------------- fused per-(b,d) row pipeline
__global__ __launch_bounds__(256) void fused_fft(u16* __restrict__ x3T,
                                                 const float2* __restrict__ tw,
                                                 const float2* __restrict__ h0f,
                                                 const float* __restrict__ w_short,
                                                 const float* __restrict__ b_short,
                                                 const float* __restrict__ w_cond1,
                                                 const float* __restrict__ b_cond1,
                                                 const float* __restrict__ w_cond2,
                                                 const float* __restrict__ b_cond2) {
  __shared__ float re[8192];
  __shared__ float im[8192];
  const int d = blockIdx.x, tid = threadIdx.x;
  u16* g0 = x3T + (size_t)d * 8192;
  const u16* g1 = x3T + (size_t)(768 + d) * 8192;
  const u16* g2 = x3T + (size_t)(1536 + d) * 8192;

  const float q0 = w_cond1[d * 3], q1 = w_cond1[d * 3 + 1], q2 = w_cond1[d * 3 + 2], bc1 = b_cond1[d];
  const float t00 = w_short[d * 3], t01 = w_short[d * 3 + 1], t02 = w_short[d * 3 + 2], bs0 = b_short[d];
  const float t10 = w_short[(768 + d) * 3], t11 = w_short[(768 + d) * 3 + 1], t12 = w_short[(768 + d) * 3 + 2], bs1 = b_short[768 + d];
  const float t20 = w_short[(1536 + d) * 3], t21 = w_short[(1536 + d) * 3 + 1], t22 = w_short[(1536 + d) * 3 + 2], bs2 = b_short[1536 + d];

  // -------- conv phase: re <- g0, im <- g2; z = hc + i*y
  for (int j = 0; j < 32; ++j) { const int s = tid + j * 256; re[LP(s)] = bf2f(g0[s]); im[LP(s)] = bf2f(g2[s]); }
  __syncthreads();
  float ty[32], th[32];
#pragma unroll
  for (int j = 0; j < 32; ++j) {
    const int s = tid + j * 256;
    const float am = s ? re[LP(s - 1)] : 0.f;
    const float a  = re[LP(s)];
    const float ap = (s < 8191) ? re[LP(s + 1)] : 0.f;
    const float bm = s ? im[LP(s - 1)] : 0.f;
    const float bv = im[LP(s)];
    const float bp = (s < 8191) ? im[LP(s + 1)] : 0.f;
    const float s1v = t00 * am + t01 * a + t02 * ap + bs0;
    const float vvv = t20 * bm + t21 * bv + t22 * bp + bs2;
    ty[j] = s1v * vvv;
    th[j] = q0 * bm + q1 * bv + q2 * bp + bc1;
  }
  __syncthreads();
#pragma unroll
  for (int j = 0; j < 32; ++j) { const int s = tid + j * 256; re[LP(s)] = th[j]; im[LP(s)] = ty[j]; }
  __syncthreads();

  fwd8192(re, im, tw, tid);          // Z = FFT(hc + i*y), bit-reversed layout

  // -------- two-for-one unpack; hm = |Hc|, Y kept in regs
  float hm[17], yr[17], yi[17];
#pragma unroll
  for (int j = 0; j < 17; ++j) {
    const int k = tid + j * 256;
    if (k <= 4096) {
      const int pz = LP(BREV13(k));
      const int pm = LP(BREV13((8192 - k) & 8191));
      const float zr = re[pz], zi = im[pz];
      const float mr = re[pm], mi = im[pm];
      const float hcr = 0.5f * (zr + mr), hci = 0.5f * (zi - mi);
      hm[j] = sqrtf(hcr * hcr + hci * hci);
      yr[j] = 0.5f * (zi + mi);
      yi[j] = 0.5f * (mr - zr);
    }
  }
  __syncthreads();
#pragma unroll
  for (int j = 0; j < 17; ++j) { const int k = tid + j * 256; if (k <= 4096) re[LP(k)] = hm[j]; }
  __syncthreads();

  // -------- h_adapt + G = Y * (h0f + ha)
  const float c0 = w_cond2[d * 3], c1 = w_cond2[d * 3 + 1], c2 = w_cond2[d * 3 + 2], bb2 = b_cond2[d];
  const float2* H0 = h0f + (size_t)d * 4097;
  float gr[17], gi[17];
#pragma unroll
  for (int j = 0; j < 17; ++j) {
    const int k = tid + j * 256;
    if (k <= 4096) {
      const float a = k ? re[LP(k - 1)] : 0.f;
      const float m = re[LP(k)];
      const float z = (k < 4096) ? re[LP(k + 1)] : 0.f;
      const float ha = c0 * a + c1 * m + c2 * z + bb2;
      const float2 h = H0[k];
      const float hr = h.x + ha, hi = h.y;
      gr[j] = yr[j] * hr - yi[j] * hi;
      gi[j] = yr[j] * hi + yi[j] * hr;
      if (k == 0 || k == 4096) gi[j] = 0.f;   // irfft ignores imag of bins 0, N/2
    }
  }
  __syncthreads();
#pragma unroll
  for (int j = 0; j < 17; ++j) {
    const int k = tid + j * 256;
    if (k <= 4096) { re[LP(k)] = gr[j]; im[LP(k)] = gi[j]; }
  }
  __syncthreads();

  // -------- half-size packing Zc[k] = E^[k] + i*O^[k]; store conj(Zc) bit-reversed
  float zr2[16], zi2[16];
#pragma unroll
  for (int j = 0; j < 16; ++j) {
    const int kc = tid + j * 256;
    const int mm = 4096 - kc;
    const float ga = re[LP(kc)], gb = im[LP(kc)];
    const float gc = re[LP(mm)], gd = im[LP(mm)];
    const float Er = 0.5f * (ga + gc), Ei = 0.5f * (gb - gd);
    const float Pr = 0.5f * (ga - gc), Pi = 0.5f * (gb + gd);
    const float2 w = tw[kc];                   // e^{-2pi i k/8192}; need * conj(w)
    const float Or = Pr * w.x + Pi * w.y;
    const float Oi = Pi * w.x - Pr * w.y;
    zr2[j] = Er - Oi;
    zi2[j] = -(Ei + Or);
  }
  __syncthreads();
#pragma unroll
  for (int j = 0; j < 16; ++j) {
    const int kc = tid + j * 256;
    const int p = LP(BREV12(kc));
    re[p] = zr2[j]; im[p] = zi2[j];
  }
  // stage g1 into the free upper LDS halves (hidden under inverse FFT barriers)
  for (int j = 0; j < 32; ++j) {
    const int s = tid + j * 256;
    const float v = bf2f(g1[s]);
    if (s < 4096) re[4096 + LP(s)] = v;
    else          im[4096 + LP(s - 4096)] = v;
  }
  __syncthreads();

  inv4096(re, im, tw, tid);          // out[m]: e[m]=Re/M, o[m]=-Im/M, natural order

  // -------- final: y2 = irfft * conv3(g1,ws1) -> g0 (bf16)
#define G1AT(s) ((s) < 4096 ? re[4096 + LP(s)] : im[4096 + LP((s) - 4096)])
  const float invM = 1.0f / 4096.0f;
#pragma unroll
  for (int j = 0; j < 32; ++j) {
    const int s = tid + j * 256;
    const int p = LP(s >> 1);
    const float xs = ((s & 1) ? -im[p] : re[p]) * invM;
    const float gm = s ? G1AT(s - 1) : 0.f;
    const float gcv = G1AT(s);
    const float gp = (s < 8191) ? G1AT(s + 1) : 0.f;
    const float s2v = t10 * gm + t11 * gcv + t12 * gp + bs1;
    g0[s] = f2bf(xs * s2v);
  }
#undef G1AT
}

// ---------------------------------------------------------------- y2 rows (768 x 8192) -> y2b (8192 x 768) bf16
__global__ __launch_bounds__(256) void y2t(const u16* __restrict__ y2rows, u16* __restrict__ y2b) {
  __shared__ u16 T[64][65];
  const int d0 = blockIdx.x * 64, s0 = blockIdx.y * 64;
  const int c = threadIdx.x & 63, r0 = threadIdx.x >> 6;
#pragma unroll
  for (int i = 0; i < 16; ++i) {
    const int r = r0 + i * 4;
    T[r][c] = y2rows[(size_t)(d0 + r) * 8192 + s0 + c];
  }
  __syncthreads();
#pragma unroll
  for (int i = 0; i < 16; ++i) {
    const int r = r0 + i * 4;
    y2b[(size_t)(s0 + r) * 768 + d0 + c] = T[c][r];
  }
}

// ---------------------------------------------------------------- launch
extern "C" void kernel_launch(void* const* d_in, const int* in_sizes, int n_in,
                              void* d_out, int out_size, void* d_ws, size_t ws_size,
                              hipStream_t stream) {
  (void)in_sizes; (void)n_in; (void)out_size; (void)ws_size;
  const float* x       = (const float*)d_in[0];
  const float* w_in    = (const float*)d_in[1];
  const float* b_in    = (const float*)d_in[2];
  const float* w_short = (const float*)d_in[3];
  const float* b_short = (const float*)d_in[4];
  const float* w_cond1 = (const float*)d_in[5];
  const float* b_cond1 = (const float*)d_in[6];
  const float* w_cond2 = (const float*)d_in[7];
  const float* b_cond2 = (const float*)d_in[8];
  const float* h0      = (const float*)d_in[9];
  const float* w_out   = (const float*)d_in[10];
  const float* b_out   = (const float*)d_in[11];

  float* ws = (float*)d_ws;
  float2* tw     = (float2*)ws;                          // [0, 16384)
  float2* h0f    = (float2*)(ws + 16384);                // [16384, 6309376)
  u16*    xb     = (u16*)(ws + 6309376);                 // [6309376, 9455104)
  u16*    w_inb  = (u16*)(ws + 9455104);                 // [9455104, 10339840)
  u16*    w_outb = (u16*)(ws + 10339840);                // [10339840, 10634752)
  u16*    x3Tb   = (u16*)(ws + 10634752);                // [10634752, 20071936)
  float*  h0T    = (float*)(ws + 6309376);               // transient, dead before xb.. written
  u16*    y2b    = x3Tb + 6291456;                       // aliases g1/g2 after fused_fft

  twfill<<<32, 256, 0, stream>>>(tw);
  transp<<<dim3(12, 128), 256, 0, stream>>>(h0, h0T);
  fft_h0_k<<<768, 256, 0, stream>>>(h0T, tw, h0f);
  cvt_bf16<<<864, 256, 0, stream>>>(w_in, w_inb, 221184);
  cvt_bf16<<<288, 256, 0, stream>>>(w_out, w_outb, 73728);

  for (int b = 0; b < 4; ++b) {
    cvt_bf16<<<3072, 256, 0, stream>>>(x + (size_t)b * 6291456, xb, 786432);
    gemm_bt<1><<<dim3(64, 18), 256, 0, stream>>>(w_inb, xb, b_in, x3Tb, 8192, 768);
    fused_fft<<<768, 256, 0, stream>>>(x3Tb, tw, h0f,
                                       w_short, b_short, w_cond1, b_cond1, w_cond2, b_cond2);
    y2t<<<dim3(12, 128), 256, 0, stream>>>(x3Tb, y2b);
    gemm_bt<0><<<dim3(6, 64), 256, 0, stream>>>(y2b, w_outb, b_out,
                                                (float*)d_out + (size_t)b * 6291456, 768, 768);
  }
}

// Round 6
// 807.478 us; speedup vs baseline: 4.0449x; 1.0767x over previous
//
#include <hip/hip_runtime.h>
#include <math.h>

// B=4, S=8192, D=768, W=3D=2304
// ws (floats): tw f32x2[8192]            [0       .. 16384)
//              h0f f32x2[768*4097]       [16384   .. 6309376)
//              xb   bf16 6291456 u16     [6309376 .. 9455104)
//              w_inb bf16 1769472 u16    [9455104 .. 10339840)
//              w_outb bf16 589824 u16    [10339840.. 10634752)
//              x3Tb bf16 18874368 u16    [10634752.. 20071936)   total 80.3 MB
// h0T (fp32, transient) aliases xb.. regions before they're written.
// y2b (bf16) aliases x3Tb's g1/g2 rows after fused_fft.

typedef unsigned short u16;
typedef short s16x8 __attribute__((ext_vector_type(8)));
typedef float f32x4 __attribute__((ext_vector_type(4)));
typedef u16 u16x8 __attribute__((ext_vector_type(8)));

#define LP(i) ((i) ^ ((i) >> 8))            // LDS swizzle, involution, keeps 12/13-bit ranges
#define BREV13(k) ((int)(__brev((unsigned)(k)) >> 19))
#define BREV12(k) ((int)(__brev((unsigned)(k)) >> 20))
#define CMUL(rr, ri, xr, xi, wr, wi) { rr = (xr)*(wr) - (xi)*(wi); ri = (xr)*(wi) + (xi)*(wr); }

__device__ __forceinline__ u16 f2bf(float f) {
  unsigned u = __float_as_uint(f);
  u = (u + 0x7FFFu + ((u >> 16) & 1u)) >> 16;
  return (u16)u;
}
__device__ __forceinline__ float bf2f(u16 u) { return __uint_as_float(((unsigned)u) << 16); }

__device__ __forceinline__ void glds16(const void* g, void* l) {
  __builtin_amdgcn_global_load_lds((const __attribute__((address_space(1))) unsigned*)g,
                                   (__attribute__((address_space(3))) unsigned*)l, 16, 0, 0);
}

// ---------------------------------------------------------------- float -> bf16
__global__ __launch_bounds__(256) void cvt_bf16(const float* __restrict__ in,
                                                u16* __restrict__ out, int n8) {
  const int i = blockIdx.x * 256 + threadIdx.x;
  if (i < n8) {
    const float4 a = ((const float4*)in)[i * 2];
    const float4 b = ((const float4*)in)[i * 2 + 1];
    u16x8 r;
    r[0] = f2bf(a.x); r[1] = f2bf(a.y); r[2] = f2bf(a.z); r[3] = f2bf(a.w);
    r[4] = f2bf(b.x); r[5] = f2bf(b.y); r[6] = f2bf(b.z); r[7] = f2bf(b.w);
    ((u16x8*)out)[i] = r;
  }
}

// ---------------------------------------------------------------- MFMA GEMM
template <int BIAS_M>
__global__ __launch_bounds__(256) void gemm_bt(const u16* __restrict__ A,
                                               const u16* __restrict__ B,
                                               const float* __restrict__ bias,
                                               void* __restrict__ Cout,
                                               int N, int K) {
  __shared__ __align__(16) u16 As[4096];
  __shared__ __align__(16) u16 Bs[4096];
  const int tid = threadIdx.x;
  const int w = tid >> 6, l = tid & 63;
  const int m0 = blockIdx.y * 128, n0 = blockIdx.x * 128;
  const int wr = w >> 1, wc = w & 1;
  const int lr = l & 15, kc = l >> 4;

  const int p0 = w * 64 + l;
  const int p1 = p0 + 256;
  const int sl0 = (p0 & 7) ^ ((p0 >> 3) & 7);
  const int sl1 = (p1 & 7) ^ ((p1 >> 3) & 7);
  const int r0 = ((p0 >> 3) << 1) | (sl0 >> 2), ka = (sl0 & 3) << 3;
  const int r1 = ((p1 >> 3) << 1) | (sl1 >> 2), kb = (sl1 & 3) << 3;
  const u16* gA0 = A + (size_t)(m0 + r0) * K + ka;
  const u16* gA1 = A + (size_t)(m0 + r1) * K + kb;
  const u16* gB0 = B + (size_t)(n0 + r0) * K + ka;
  const u16* gB1 = B + (size_t)(n0 + r1) * K + kb;
  u16* lA0 = &As[(size_t)w * 512];
  u16* lA1 = &As[(size_t)(4 + w) * 512];
  u16* lB0 = &Bs[(size_t)w * 512];
  u16* lB1 = &Bs[(size_t)(4 + w) * 512];

  f32x4 acc[4][4] = {};

  for (int k0 = 0; k0 < K; k0 += 32) {
    glds16(gA0 + k0, lA0);
    glds16(gA1 + k0, lA1);
    glds16(gB0 + k0, lB0);
    glds16(gB1 + k0, lB1);
    __syncthreads();
    s16x8 af[4], bfr[4];
#pragma unroll
    for (int mi = 0; mi < 4; ++mi) {
      const int row = wr * 64 + mi * 16 + lr;
      const int slot = (((lr & 1) << 2) | kc) ^ ((lr >> 1) & 7);
      af[mi] = *(const s16x8*)&As[(row >> 1) * 64 + slot * 8];
    }
#pragma unroll
    for (int ni = 0; ni < 4; ++ni) {
      const int row = wc * 64 + ni * 16 + lr;
      const int slot = (((lr & 1) << 2) | kc) ^ ((lr >> 1) & 7);
      bfr[ni] = *(const s16x8*)&Bs[(row >> 1) * 64 + slot * 8];
    }
#pragma unroll
    for (int mi = 0; mi < 4; ++mi)
#pragma unroll
      for (int ni = 0; ni < 4; ++ni)
        acc[mi][ni] = __builtin_amdgcn_mfma_f32_16x16x32_bf16(af[mi], bfr[ni], acc[mi][ni], 0, 0, 0);
    __syncthreads();
  }

  const int rbase = m0 + wr * 64 + (kc << 2);
  const int cbase = n0 + wc * 64 + lr;
#pragma unroll
  for (int mi = 0; mi < 4; ++mi)
#pragma unroll
    for (int j = 0; j < 4; ++j) {
      const int row = rbase + mi * 16 + j;
      const float bm = BIAS_M ? bias[row] : 0.f;
#pragma unroll
      for (int ni = 0; ni < 4; ++ni) {
        const int col = cbase + ni * 16;
        const float v = acc[mi][ni][j] + (BIAS_M ? bm : bias[col]);
        if (BIAS_M) ((u16*)Cout)[(size_t)row * N + col] = f2bf(v);
        else        ((float*)Cout)[(size_t)row * N + col] = v;
      }
    }
}

// ---------------------------------------------------------------- twiddles exp(-2pi i k/8192), k<8192
__global__ void twfill(float2* __restrict__ tw) {
  const int k = blockIdx.x * 256 + threadIdx.x;
  if (k < 8192) {
    const double t = -2.0 * 3.14159265358979323846 * (double)k / 8192.0;
    tw[k] = make_float2((float)cos(t), (float)sin(t));
  }
}

// ---------------------------------------------------------------- h0 (8192 x 768) -> h0T (768 x 8192) fp32
__global__ __launch_bounds__(256) void transp(const float* __restrict__ in, float* __restrict__ out) {
  __shared__ float T[64][65];
  const int d0 = blockIdx.x * 64, s0 = blockIdx.y * 64;
  const int c = threadIdx.x & 63, r0 = threadIdx.x >> 6;
#pragma unroll
  for (int i = 0; i < 16; ++i) {
    const int r = r0 + i * 4;
    T[r][c] = in[(size_t)(s0 + r) * 768 + d0 + c];
  }
  __syncthreads();
#pragma unroll
  for (int i = 0; i < 16; ++i) {
    const int r = r0 + i * 4;
    out[(size_t)(d0 + r) * 8192 + s0 + c] = T[c][r];
  }
}

// ---------------------------------------------------------------- forward 8192 FFT: 6 radix-4 + 1 radix-2
// Output layout = 13-bit bit-reversal. NT = threads per block.
template <int NT>
__device__ __forceinline__ void fwd8192(float* re, float* im, const float2* __restrict__ tw, int tid) {
  for (int s = 13; s >= 3; s -= 2) {
    const int h = 1 << (s - 2);
    const int e = 13 - s;
#pragma unroll 2
    for (int t = 0; t < 2048 / NT; ++t) {
      const int g = tid + t * NT;
      const int b = g >> (s - 2);
      const int j = g & (h - 1);
      const int base = (b << s) | j;
      const int p0 = LP(base), p1 = LP(base + h), p2 = LP(base + 2 * h), p3 = LP(base + 3 * h);
      const float ar = re[p0], ai = im[p0];
      const float br = re[p1], bi = im[p1];
      const float cr = re[p2], ci = im[p2];
      const float dr = re[p3], di = im[p3];
      const float2 w1 = tw[j << e];
      const float2 w2 = tw[(2 * j) << e];
      const float2 w3 = tw[(3 * j) << e];
      const float apr = ar + cr, api = ai + ci, amr = ar - cr, ami = ai - ci;
      const float bpr = br + dr, bpi = bi + di, bmr = br - dr, bmi = bi - di;
      re[p0] = apr + bpr; im[p0] = api + bpi;
      const float x1r = apr - bpr, x1i = api - bpi;
      CMUL(re[p1], im[p1], x1r, x1i, w2.x, w2.y);
      const float x2r = amr + bmi, x2i = ami - bmr;      // (a-c) - i(b-d)
      CMUL(re[p2], im[p2], x2r, x2i, w1.x, w1.y);
      const float x3r = amr - bmi, x3i = ami + bmr;      // (a-c) + i(b-d)
      CMUL(re[p3], im[p3], x3r, x3i, w3.x, w3.y);
    }
    __syncthreads();
  }
  // final radix-2, stride 1, twiddle 1
#pragma unroll 4
  for (int t = 0; t < 4096 / NT; ++t) {
    const int g = tid + t * NT;
    const int p = LP(2 * g), q = LP(2 * g + 1);
    const float ur = re[p], ui = im[p];
    const float vr = re[q], vi = im[q];
    re[p] = ur + vr; im[p] = ui + vi;
    re[q] = ur - vr; im[q] = ui - vi;
  }
  __syncthreads();
}

// ---------------------------------------------------------------- inverse-core 4096 FFT (forward twiddles; caller conjugates)
// 6 pure radix-4 DIT stages; input at 12-bit bit-reversed slots, output natural.
template <int NT>
__device__ __forceinline__ void inv4096(float* re, float* im, const float2* __restrict__ tw, int tid) {
  for (int s = 1; s <= 11; s += 2) {
    const int h = 1 << (s - 1);
    const int e = 12 - s;
#pragma unroll 2
    for (int t = 0; t < 1024 / NT; ++t) {
      const int g = tid + t * NT;
      const int b = g >> (s - 1);
      const int j = g & (h - 1);
      const int base = (b << (s + 1)) | j;
      const int p0 = LP(base), p1 = LP(base + h), p2 = LP(base + 2 * h), p3 = LP(base + 3 * h);
      const float ar = re[p0], ai = im[p0];
      const float br = re[p1], bi = im[p1];
      const float cr = re[p2], ci = im[p2];
      const float dr = re[p3], di = im[p3];
      const float2 w1 = tw[j << e];
      const float2 w2 = tw[(2 * j) << e];
      float vbr, vbi, vdr, vdi;
      CMUL(vbr, vbi, br, bi, w2.x, w2.y);
      CMUL(vdr, vdi, dr, di, w2.x, w2.y);
      const float a1r = ar + vbr, a1i = ai + vbi;
      const float b1r = ar - vbr, b1i = ai - vbi;
      const float c1r = cr + vdr, c1i = ci + vdi;
      const float d1r = cr - vdr, d1i = ci - vdi;
      float t1r, t1i, ur, ui;
      CMUL(t1r, t1i, c1r, c1i, w1.x, w1.y);
      CMUL(ur, ui, d1r, d1i, w1.y, -w1.x);               // x * (-i*w1)
      re[p0] = a1r + t1r; im[p0] = a1i + t1i;
      re[p2] = a1r - t1r; im[p2] = a1i - t1i;
      re[p1] = b1r + ur;  im[p1] = b1i + ui;
      re[p3] = b1r - ur;  im[p3] = b1i - ui;
    }
    __syncthreads();
  }
}

// ---------------------------------------------------------------- h0f[d,k] = rfft(h0T row d) (fp32), 512 thr
__global__ __launch_bounds__(512, 4) void fft_h0_k(const float* __restrict__ h0T,
                                                   const float2* __restrict__ tw,
                                                   float2* __restrict__ h0f) {
  __shared__ float re[8192];
  __shared__ float im[8192];
  const int d = blockIdx.x, tid = threadIdx.x;
  const float* src = h0T + (size_t)d * 8192;
  for (int s = tid; s < 8192; s += 512) { re[LP(s)] = src[s]; im[LP(s)] = 0.f; }
  __syncthreads();
  fwd8192<512>(re, im, tw, tid);
  for (int k = tid; k <= 4096; k += 512) {
    const int p = LP(BREV13(k));
    h0f[(size_t)d * 4097 + k] = make_float2(re[p], im[p]);
  }
}

// ---------------------------------------------------------------- fused per-(b,d) row pipeline, 512 thr
__global__ __launch_bounds__(512, 4) void fused_fft(u16* __restrict__ x3T,
                                                    const float2* __restrict__ tw,
                                                    const float2* __restrict__ h0f,
                                                    const float* __restrict__ w_short,
                                                    const float* __restrict__ b_short,
                                                    const float* __restrict__ w_cond1,
                                                    const float* __restrict__ b_cond1,
                                                    const float* __restrict__ w_cond2,
                                                    const float* __restrict__ b_cond2) {
  __shared__ float re[8192];
  __shared__ float im[8192];
  const int d = blockIdx.x, tid = threadIdx.x;
  u16* g0 = x3T + (size_t)d * 8192;
  const u16* g1 = x3T + (size_t)(768 + d) * 8192;
  const u16* g2 = x3T + (size_t)(1536 + d) * 8192;

  const float q0 = w_cond1[d * 3], q1 = w_cond1[d * 3 + 1], q2 = w_cond1[d * 3 + 2], bc1 = b_cond1[d];
  const float t00 = w_short[d * 3], t01 = w_short[d * 3 + 1], t02 = w_short[d * 3 + 2], bs0 = b_short[d];
  const float t10 = w_short[(768 + d) * 3], t11 = w_short[(768 + d) * 3 + 1], t12 = w_short[(768 + d) * 3 + 2], bs1 = b_short[768 + d];
  const float t20 = w_short[(1536 + d) * 3], t21 = w_short[(1536 + d) * 3 + 1], t22 = w_short[(1536 + d) * 3 + 2], bs2 = b_short[1536 + d];

  // -------- conv phase: re <- g0, im <- g2; z = hc + i*y
  for (int j = 0; j < 16; ++j) { const int s = tid + j * 512; re[LP(s)] = bf2f(g0[s]); im[LP(s)] = bf2f(g2[s]); }
  __syncthreads();
  float ty[16], th[16];
#pragma unroll
  for (int j = 0; j < 16; ++j) {
    const int s = tid + j * 512;
    const float am = s ? re[LP(s - 1)] : 0.f;
    const float a  = re[LP(s)];
    const float ap = (s < 8191) ? re[LP(s + 1)] : 0.f;
    const float bm = s ? im[LP(s - 1)] : 0.f;
    const float bv = im[LP(s)];
    const float bp = (s < 8191) ? im[LP(s + 1)] : 0.f;
    const float s1v = t00 * am + t01 * a + t02 * ap + bs0;
    const float vvv = t20 * bm + t21 * bv + t22 * bp + bs2;
    ty[j] = s1v * vvv;
    th[j] = q0 * bm + q1 * bv + q2 * bp + bc1;
  }
  __syncthreads();
#pragma unroll
  for (int j = 0; j < 16; ++j) { const int s = tid + j * 512; re[LP(s)] = th[j]; im[LP(s)] = ty[j]; }
  __syncthreads();

  fwd8192<512>(re, im, tw, tid);     // Z = FFT(hc + i*y), bit-reversed layout

  // -------- two-for-one unpack; hm = |Hc|, Y kept in regs
  float hm[9], yr[9], yi[9];
#pragma unroll
  for (int j = 0; j < 9; ++j) {
    const int k = tid + j * 512;
    if (k <= 4096) {
      const int pz = LP(BREV13(k));
      const int pm = LP(BREV13((8192 - k) & 8191));
      const float zr = re[pz], zi = im[pz];
      const float mr = re[pm], mi = im[pm];
      const float hcr = 0.5f * (zr + mr), hci = 0.5f * (zi - mi);
      hm[j] = sqrtf(hcr * hcr + hci * hci);
      yr[j] = 0.5f * (zi + mi);
      yi[j] = 0.5f * (mr - zr);
    }
  }
  __syncthreads();
#pragma unroll
  for (int j = 0; j < 9; ++j) { const int k = tid + j * 512; if (k <= 4096) re[LP(k)] = hm[j]; }
  __syncthreads();

  // -------- h_adapt + G = Y * (h0f + ha)
  const float c0 = w_cond2[d * 3], c1 = w_cond2[d * 3 + 1], c2 = w_cond2[d * 3 + 2], bb2 = b_cond2[d];
  const float2* H0 = h0f + (size_t)d * 4097;
  float gr[9], gi[9];
#pragma unroll
  for (int j = 0; j < 9; ++j) {
    const int k = tid + j * 512;
    if (k <= 4096) {
      const float a = k ? re[LP(k - 1)] : 0.f;
      const float m = re[LP(k)];
      const float z = (k < 4096) ? re[LP(k + 1)] : 0.f;
      const float ha = c0 * a + c1 * m + c2 * z + bb2;
      const float2 h = H0[k];
      const float hr = h.x + ha, hi = h.y;
      gr[j] = yr[j] * hr - yi[j] * hi;
      gi[j] = yr[j] * hi + yi[j] * hr;
      if (k == 0 || k == 4096) gi[j] = 0.f;   // irfft ignores imag of bins 0, N/2
    }
  }
  __syncthreads();
#pragma unroll
  for (int j = 0; j < 9; ++j) {
    const int k = tid + j * 512;
    if (k <= 4096) { re[LP(k)] = gr[j]; im[LP(k)] = gi[j]; }
  }
  __syncthreads();

  // -------- half-size packing Zc[k] = E^[k] + i*O^[k]; store conj(Zc) bit-reversed
  float zr2[8], zi2[8];
#pragma unroll
  for (int j = 0; j < 8; ++j) {
    const int kc = tid + j * 512;
    const int mm = 4096 - kc;
    const float ga = re[LP(kc)], gb = im[LP(kc)];
    const float gc = re[LP(mm)], gd = im[LP(mm)];
    const float Er = 0.5f * (ga + gc), Ei = 0.5f * (gb - gd);
    const float Pr = 0.5f * (ga - gc), Pi = 0.5f * (gb + gd);
    const float2 w = tw[kc];                   // e^{-2pi i k/8192}; need * conj(w)
    const float Or = Pr * w.x + Pi * w.y;
    const float Oi = Pi * w.x - Pr * w.y;
    zr2[j] = Er - Oi;
    zi2[j] = -(Ei + Or);
  }
  __syncthreads();
#pragma unroll
  for (int j = 0; j < 8; ++j) {
    const int kc = tid + j * 512;
    const int p = LP(BREV12(kc));
    re[p] = zr2[j]; im[p] = zi2[j];
  }
  // stage g1 into the free upper LDS halves (hidden under inverse FFT barriers)
  for (int j = 0; j < 16; ++j) {
    const int s = tid + j * 512;
    const float v = bf2f(g1[s]);
    if (s < 4096) re[4096 + LP(s)] = v;
    else          im[4096 + LP(s - 4096)] = v;
  }
  __syncthreads();

  inv4096<512>(re, im, tw, tid);     // out[m]: e[m]=Re/M, o[m]=-Im/M, natural order

  // -------- final: y2 = irfft * conv3(g1,ws1) -> g0 (bf16)
#define G1AT(s) ((s) < 4096 ? re[4096 + LP(s)] : im[4096 + LP((s) - 4096)])
  const float invM = 1.0f / 4096.0f;
#pragma unroll
  for (int j = 0; j < 16; ++j) {
    const int s = tid + j * 512;
    const int p = LP(s >> 1);
    const float xs = ((s & 1) ? -im[p] : re[p]) * invM;
    const float gm = s ? G1AT(s - 1) : 0.f;
    const float gcv = G1AT(s);
    const float gp = (s < 8191) ? G1AT(s + 1) : 0.f;
    const float s2v = t10 * gm + t11 * gcv + t12 * gp + bs1;
    g0[s] = f2bf(xs * s2v);
  }
#undef G1AT
}

// ---------------------------------------------------------------- y2 rows (768 x 8192) -> y2b (8192 x 768) bf16
__global__ __launch_bounds__(256) void y2t(const u16* __restrict__ y2rows, u16* __restrict__ y2b) {
  __shared__ u16 T[64][65];
  const int d0 = blockIdx.x * 64, s0 = blockIdx.y * 64;
  const int c = threadIdx.x & 63, r0 = threadIdx.x >> 6;
#pragma unroll
  for (int i = 0; i < 16; ++i) {
    const int r = r0 + i * 4;
    T[r][c] = y2rows[(size_t)(d0 + r) * 8192 + s0 + c];
  }
  __syncthreads();
#pragma unroll
  for (int i = 0; i < 16; ++i) {
    const int r = r0 + i * 4;
    y2b[(size_t)(s0 + r) * 768 + d0 + c] = T[c][r];
  }
}

// ---------------------------------------------------------------- launch
extern "C" void kernel_launch(void* const* d_in, const int* in_sizes, int n_in,
                              void* d_out, int out_size, void* d_ws, size_t ws_size,
                              hipStream_t stream) {
  (void)in_sizes; (void)n_in; (void)out_size; (void)ws_size;
  const float* x       = (const float*)d_in[0];
  const float* w_in    = (const float*)d_in[1];
  const float* b_in    = (const float*)d_in[2];
  const float* w_short = (const float*)d_in[3];
  const float* b_short = (const float*)d_in[4];
  const float* w_cond1 = (const float*)d_in[5];
  const float* b_cond1 = (const float*)d_in[6];
  const float* w_cond2 = (const float*)d_in[7];
  const float* b_cond2 = (const float*)d_in[8];
  const float* h0      = (const float*)d_in[9];
  const float* w_out   = (const float*)d_in[10];
  const float* b_out   = (const float*)d_in[11];

  float* ws = (float*)d_ws;
  float2* tw     = (float2*)ws;                          // [0, 16384)
  float2* h0f    = (float2*)(ws + 16384);                // [16384, 6309376)
  u16*    xb     = (u16*)(ws + 6309376);                 // [6309376, 9455104)
  u16*    w_inb  = (u16*)(ws + 9455104);                 // [9455104, 10339840)
  u16*    w_outb = (u16*)(ws + 10339840);                // [10339840, 10634752)
  u16*    x3Tb   = (u16*)(ws + 10634752);                // [10634752, 20071936)
  float*  h0T    = (float*)(ws + 6309376);               // transient, dead before xb.. written
  u16*    y2b    = x3Tb + 6291456;                       // aliases g1/g2 after fused_fft

  twfill<<<32, 256, 0, stream>>>(tw);
  transp<<<dim3(12, 128), 256, 0, stream>>>(h0, h0T);
  fft_h0_k<<<768, 512, 0, stream>>>(h0T, tw, h0f);
  cvt_bf16<<<864, 256, 0, stream>>>(w_in, w_inb, 221184);
  cvt_bf16<<<288, 256, 0, stream>>>(w_out, w_outb, 73728);

  for (int b = 0; b < 4; ++b) {
    cvt_bf16<<<3072, 256, 0, stream>>>(x + (size_t)b * 6291456, xb, 786432);
    gemm_bt<1><<<dim3(64, 18), 256, 0, stream>>>(w_inb, xb, b_in, x3Tb, 8192, 768);
    fused_fft<<<768, 512, 0, stream>>>(x3Tb, tw, h0f,
                                       w_short, b_short, w_cond1, b_cond1, w_cond2, b_cond2);
    y2t<<<dim3(12, 128), 256, 0, stream>>>(x3Tb, y2b);
    gemm_bt<0><<<dim3(6, 64), 256, 0, stream>>>(y2b, w_outb, b_out,
                                                (float*)d_out + (size_t)b * 6291456, 768, 768);
  }
}

// Round 7
// 749.135 us; speedup vs baseline: 4.3599x; 1.0779x over previous
//
#include <hip/hip_runtime.h>
#include <math.h>

// B=4, S=8192, D=768, W=3D=2304
// ws (floats): tw f32x2[8192]            [0       .. 16384)
//              h0f f32x2[768*4097]       [16384   .. 6309376)
//              xb   bf16 6291456 u16     [6309376 .. 9455104)
//              w_inb bf16 1769472 u16    [9455104 .. 10339840)
//              w_outb bf16 589824 u16    [10339840.. 10634752)
//              x3Tb bf16 18874368 u16    [10634752.. 20071936)   total 80.3 MB
// h0T (fp32, transient) aliases xb.. regions before they're written.
// y2b (bf16) aliases x3Tb's g1/g2 rows after fused_fft.

typedef unsigned short u16;
typedef short s16x8 __attribute__((ext_vector_type(8)));
typedef float f32x4 __attribute__((ext_vector_type(4)));
typedef u16 u16x8 __attribute__((ext_vector_type(8)));

// LDS slot swizzle: fold bits[9:5] into the bank index. Bijective involution,
// maps [0,4096)->[0,4096) and [0,8192)->[0,8192). Spreads stride-2^s (s>=3)
// butterfly accesses across all 32 banks (old i^(i>>8) was inert below 256).
#define LP(i) ((i) ^ (((i) >> 5) & 31))
#define BREV13(k) ((int)(__brev((unsigned)(k)) >> 19))
#define BREV12(k) ((int)(__brev((unsigned)(k)) >> 20))
#define CMUL(rr, ri, xr, xi, wr, wi) { rr = (xr)*(wr) - (xi)*(wi); ri = (xr)*(wi) + (xi)*(wr); }

__device__ __forceinline__ u16 f2bf(float f) {
  unsigned u = __float_as_uint(f);
  u = (u + 0x7FFFu + ((u >> 16) & 1u)) >> 16;
  return (u16)u;
}
__device__ __forceinline__ float bf2f(u16 u) { return __uint_as_float(((unsigned)u) << 16); }

__device__ __forceinline__ void glds16(const void* g, void* l) {
  __builtin_amdgcn_global_load_lds((const __attribute__((address_space(1))) unsigned*)g,
                                   (__attribute__((address_space(3))) unsigned*)l, 16, 0, 0);
}

// ---------------------------------------------------------------- float -> bf16
__global__ __launch_bounds__(256) void cvt_bf16(const float* __restrict__ in,
                                                u16* __restrict__ out, int n8) {
  const int i = blockIdx.x * 256 + threadIdx.x;
  if (i < n8) {
    const float4 a = ((const float4*)in)[i * 2];
    const float4 b = ((const float4*)in)[i * 2 + 1];
    u16x8 r;
    r[0] = f2bf(a.x); r[1] = f2bf(a.y); r[2] = f2bf(a.z); r[3] = f2bf(a.w);
    r[4] = f2bf(b.x); r[5] = f2bf(b.y); r[6] = f2bf(b.z); r[7] = f2bf(b.w);
    ((u16x8*)out)[i] = r;
  }
}

// ---------------------------------------------------------------- MFMA GEMM
template <int BIAS_M>
__global__ __launch_bounds__(256) void gemm_bt(const u16* __restrict__ A,
                                               const u16* __restrict__ B,
                                               const float* __restrict__ bias,
                                               void* __restrict__ Cout,
                                               int N, int K) {
  __shared__ __align__(16) u16 As[4096];
  __shared__ __align__(16) u16 Bs[4096];
  const int tid = threadIdx.x;
  const int w = tid >> 6, l = tid & 63;
  const int m0 = blockIdx.y * 128, n0 = blockIdx.x * 128;
  const int wr = w >> 1, wc = w & 1;
  const int lr = l & 15, kc = l >> 4;

  const int p0 = w * 64 + l;
  const int p1 = p0 + 256;
  const int sl0 = (p0 & 7) ^ ((p0 >> 3) & 7);
  const int sl1 = (p1 & 7) ^ ((p1 >> 3) & 7);
  const int r0 = ((p0 >> 3) << 1) | (sl0 >> 2), ka = (sl0 & 3) << 3;
  const int r1 = ((p1 >> 3) << 1) | (sl1 >> 2), kb = (sl1 & 3) << 3;
  const u16* gA0 = A + (size_t)(m0 + r0) * K + ka;
  const u16* gA1 = A + (size_t)(m0 + r1) * K + kb;
  const u16* gB0 = B + (size_t)(n0 + r0) * K + ka;
  const u16* gB1 = B + (size_t)(n0 + r1) * K + kb;
  u16* lA0 = &As[(size_t)w * 512];
  u16* lA1 = &As[(size_t)(4 + w) * 512];
  u16* lB0 = &Bs[(size_t)w * 512];
  u16* lB1 = &Bs[(size_t)(4 + w) * 512];

  f32x4 acc[4][4] = {};

  for (int k0 = 0; k0 < K; k0 += 32) {
    glds16(gA0 + k0, lA0);
    glds16(gA1 + k0, lA1);
    glds16(gB0 + k0, lB0);
    glds16(gB1 + k0, lB1);
    __syncthreads();
    s16x8 af[4], bfr[4];
#pragma unroll
    for (int mi = 0; mi < 4; ++mi) {
      const int row = wr * 64 + mi * 16 + lr;
      const int slot = (((lr & 1) << 2) | kc) ^ ((lr >> 1) & 7);
      af[mi] = *(const s16x8*)&As[(row >> 1) * 64 + slot * 8];
    }
#pragma unroll
    for (int ni = 0; ni < 4; ++ni) {
      const int row = wc * 64 + ni * 16 + lr;
      const int slot = (((lr & 1) << 2) | kc) ^ ((lr >> 1) & 7);
      bfr[ni] = *(const s16x8*)&Bs[(row >> 1) * 64 + slot * 8];
    }
#pragma unroll
    for (int mi = 0; mi < 4; ++mi)
#pragma unroll
      for (int ni = 0; ni < 4; ++ni)
        acc[mi][ni] = __builtin_amdgcn_mfma_f32_16x16x32_bf16(af[mi], bfr[ni], acc[mi][ni], 0, 0, 0);
    __syncthreads();
  }

  const int rbase = m0 + wr * 64 + (kc << 2);
  const int cbase = n0 + wc * 64 + lr;
#pragma unroll
  for (int mi = 0; mi < 4; ++mi)
#pragma unroll
    for (int j = 0; j < 4; ++j) {
      const int row = rbase + mi * 16 + j;
      const float bm = BIAS_M ? bias[row] : 0.f;
#pragma unroll
      for (int ni = 0; ni < 4; ++ni) {
        const int col = cbase + ni * 16;
        const float v = acc[mi][ni][j] + (BIAS_M ? bm : bias[col]);
        if (BIAS_M) ((u16*)Cout)[(size_t)row * N + col] = f2bf(v);
        else        ((float*)Cout)[(size_t)row * N + col] = v;
      }
    }
}

// ---------------------------------------------------------------- twiddles exp(-2pi i k/8192), k<8192
__global__ void twfill(float2* __restrict__ tw) {
  const int k = blockIdx.x * 256 + threadIdx.x;
  if (k < 8192) {
    const double t = -2.0 * 3.14159265358979323846 * (double)k / 8192.0;
    tw[k] = make_float2((float)cos(t), (float)sin(t));
  }
}

// ---------------------------------------------------------------- h0 (8192 x 768) -> h0T (768 x 8192) fp32
__global__ __launch_bounds__(256) void transp(const float* __restrict__ in, float* __restrict__ out) {
  __shared__ float T[64][65];
  const int d0 = blockIdx.x * 64, s0 = blockIdx.y * 64;
  const int c = threadIdx.x & 63, r0 = threadIdx.x >> 6;
#pragma unroll
  for (int i = 0; i < 16; ++i) {
    const int r = r0 + i * 4;
    T[r][c] = in[(size_t)(s0 + r) * 768 + d0 + c];
  }
  __syncthreads();
#pragma unroll
  for (int i = 0; i < 16; ++i) {
    const int r = r0 + i * 4;
    out[(size_t)(d0 + r) * 8192 + s0 + c] = T[c][r];
  }
}

// ---------------------------------------------------------------- forward 8192 FFT: 6 radix-4 + 1 radix-2
// Output layout = 13-bit bit-reversal. NT = threads per block.
template <int NT>
__device__ __forceinline__ void fwd8192(float* re, float* im, const float2* __restrict__ tw, int tid) {
  for (int s = 13; s >= 3; s -= 2) {
    const int h = 1 << (s - 2);
    const int e = 13 - s;
#pragma unroll 2
    for (int t = 0; t < 2048 / NT; ++t) {
      const int g = tid + t * NT;
      const int b = g >> (s - 2);
      const int j = g & (h - 1);
      const int base = (b << s) | j;
      const int p0 = LP(base), p1 = LP(base + h), p2 = LP(base + 2 * h), p3 = LP(base + 3 * h);
      const float ar = re[p0], ai = im[p0];
      const float br = re[p1], bi = im[p1];
      const float cr = re[p2], ci = im[p2];
      const float dr = re[p3], di = im[p3];
      const float2 w1 = tw[j << e];
      const float2 w2 = tw[(2 * j) << e];
      const float2 w3 = tw[(3 * j) << e];
      const float apr = ar + cr, api = ai + ci, amr = ar - cr, ami = ai - ci;
      const float bpr = br + dr, bpi = bi + di, bmr = br - dr, bmi = bi - di;
      re[p0] = apr + bpr; im[p0] = api + bpi;
      const float x1r = apr - bpr, x1i = api - bpi;
      CMUL(re[p1], im[p1], x1r, x1i, w2.x, w2.y);
      const float x2r = amr + bmi, x2i = ami - bmr;      // (a-c) - i(b-d)
      CMUL(re[p2], im[p2], x2r, x2i, w1.x, w1.y);
      const float x3r = amr - bmi, x3i = ami + bmr;      // (a-c) + i(b-d)
      CMUL(re[p3], im[p3], x3r, x3i, w3.x, w3.y);
    }
    __syncthreads();
  }
  // final radix-2, stride 1, twiddle 1
#pragma unroll 4
  for (int t = 0; t < 4096 / NT; ++t) {
    const int g = tid + t * NT;
    const int p = LP(2 * g), q = LP(2 * g + 1);
    const float ur = re[p], ui = im[p];
    const float vr = re[q], vi = im[q];
    re[p] = ur + vr; im[p] = ui + vi;
    re[q] = ur - vr; im[q] = ui - vi;
  }
  __syncthreads();
}

// ---------------------------------------------------------------- inverse-core 4096 FFT (forward twiddles; caller conjugates)
// 6 pure radix-4 DIT stages; input at 12-bit bit-reversed slots, output natural.
template <int NT>
__device__ __forceinline__ void inv4096(float* re, float* im, const float2* __restrict__ tw, int tid) {
  for (int s = 1; s <= 11; s += 2) {
    const int h = 1 << (s - 1);
    const int e = 12 - s;
#pragma unroll 2
    for (int t = 0; t < 1024 / NT; ++t) {
      const int g = tid + t * NT;
      const int b = g >> (s - 1);
      const int j = g & (h - 1);
      const int base = (b << (s + 1)) | j;
      const int p0 = LP(base), p1 = LP(base + h), p2 = LP(base + 2 * h), p3 = LP(base + 3 * h);
      const float ar = re[p0], ai = im[p0];
      const float br = re[p1], bi = im[p1];
      const float cr = re[p2], ci = im[p2];
      const float dr = re[p3], di = im[p3];
      const float2 w1 = tw[j << e];
      const float2 w2 = tw[(2 * j) << e];
      float vbr, vbi, vdr, vdi;
      CMUL(vbr, vbi, br, bi, w2.x, w2.y);
      CMUL(vdr, vdi, dr, di, w2.x, w2.y);
      const float a1r = ar + vbr, a1i = ai + vbi;
      const float b1r = ar - vbr, b1i = ai - vbi;
      const float c1r = cr + vdr, c1i = ci + vdi;
      const float d1r = cr - vdr, d1i = ci - vdi;
      float t1r, t1i, ur, ui;
      CMUL(t1r, t1i, c1r, c1i, w1.x, w1.y);
      CMUL(ur, ui, d1r, d1i, w1.y, -w1.x);               // x * (-i*w1)
      re[p0] = a1r + t1r; im[p0] = a1i + t1i;
      re[p2] = a1r - t1r; im[p2] = a1i - t1i;
      re[p1] = b1r + ur;  im[p1] = b1i + ui;
      re[p3] = b1r - ur;  im[p3] = b1i - ui;
    }
    __syncthreads();
  }
}

// ---------------------------------------------------------------- h0f[d,k] = rfft(h0T row d) (fp32), 512 thr
__global__ __launch_bounds__(512, 2) void fft_h0_k(const float* __restrict__ h0T,
                                                   const float2* __restrict__ tw,
                                                   float2* __restrict__ h0f) {
  __shared__ float re[8192];
  __shared__ float im[8192];
  const int d = blockIdx.x, tid = threadIdx.x;
  const float* src = h0T + (size_t)d * 8192;
  for (int s = tid; s < 8192; s += 512) { re[LP(s)] = src[s]; im[LP(s)] = 0.f; }
  __syncthreads();
  fwd8192<512>(re, im, tw, tid);
  for (int k = tid; k <= 4096; k += 512) {
    const int p = LP(BREV13(k));
    h0f[(size_t)d * 4097 + k] = make_float2(re[p], im[p]);
  }
}

// ---------------------------------------------------------------- fused per-(b,d) row pipeline, 512 thr
__global__ __launch_bounds__(512, 2) void fused_fft(u16* __restrict__ x3T,
                                                    const float2* __restrict__ tw,
                                                    const float2* __restrict__ h0f,
                                                    const float* __restrict__ w_short,
                                                    const float* __restrict__ b_short,
                                                    const float* __restrict__ w_cond1,
                                                    const float* __restrict__ b_cond1,
                                                    const float* __restrict__ w_cond2,
                                                    const float* __restrict__ b_cond2) {
  __shared__ float re[8192];
  __shared__ float im[8192];
  const int d = blockIdx.x, tid = threadIdx.x;
  u16* g0 = x3T + (size_t)d * 8192;
  const u16* g1 = x3T + (size_t)(768 + d) * 8192;
  const u16* g2 = x3T + (size_t)(1536 + d) * 8192;

  const float q0 = w_cond1[d * 3], q1 = w_cond1[d * 3 + 1], q2 = w_cond1[d * 3 + 2], bc1 = b_cond1[d];
  const float t00 = w_short[d * 3], t01 = w_short[d * 3 + 1], t02 = w_short[d * 3 + 2], bs0 = b_short[d];
  const float t10 = w_short[(768 + d) * 3], t11 = w_short[(768 + d) * 3 + 1], t12 = w_short[(768 + d) * 3 + 2], bs1 = b_short[768 + d];
  const float t20 = w_short[(1536 + d) * 3], t21 = w_short[(1536 + d) * 3 + 1], t22 = w_short[(1536 + d) * 3 + 2], bs2 = b_short[1536 + d];

  // -------- conv phase: re <- g0, im <- g2; z = hc + i*y
  for (int j = 0; j < 16; ++j) { const int s = tid + j * 512; re[LP(s)] = bf2f(g0[s]); im[LP(s)] = bf2f(g2[s]); }
  __syncthreads();
  float ty[16], th[16];
#pragma unroll
  for (int j = 0; j < 16; ++j) {
    const int s = tid + j * 512;
    const float am = s ? re[LP(s - 1)] : 0.f;
    const float a  = re[LP(s)];
    const float ap = (s < 8191) ? re[LP(s + 1)] : 0.f;
    const float bm = s ? im[LP(s - 1)] : 0.f;
    const float bv = im[LP(s)];
    const float bp = (s < 8191) ? im[LP(s + 1)] : 0.f;
    const float s1v = t00 * am + t01 * a + t02 * ap + bs0;
    const float vvv = t20 * bm + t21 * bv + t22 * bp + bs2;
    ty[j] = s1v * vvv;
    th[j] = q0 * bm + q1 * bv + q2 * bp + bc1;
  }
  __syncthreads();
#pragma unroll
  for (int j = 0; j < 16; ++j) { const int s = tid + j * 512; re[LP(s)] = th[j]; im[LP(s)] = ty[j]; }
  __syncthreads();

  fwd8192<512>(re, im, tw, tid);     // Z = FFT(hc + i*y), bit-reversed layout

  // -------- two-for-one unpack; hm = |Hc|, Y kept in regs
  float hm[9], yr[9], yi[9];
#pragma unroll
  for (int j = 0; j < 9; ++j) {
    const int k = tid + j * 512;
    if (k <= 4096) {
      const int pz = LP(BREV13(k));
      const int pm = LP(BREV13((8192 - k) & 8191));
      const float zr = re[pz], zi = im[pz];
      const float mr = re[pm], mi = im[pm];
      const float hcr = 0.5f * (zr + mr), hci = 0.5f * (zi - mi);
      hm[j] = sqrtf(hcr * hcr + hci * hci);
      yr[j] = 0.5f * (zi + mi);
      yi[j] = 0.5f * (mr - zr);
    }
  }
  __syncthreads();
#pragma unroll
  for (int j = 0; j < 9; ++j) { const int k = tid + j * 512; if (k <= 4096) re[LP(k)] = hm[j]; }
  __syncthreads();

  // -------- h_adapt + G = Y * (h0f + ha)
  const float c0 = w_cond2[d * 3], c1 = w_cond2[d * 3 + 1], c2 = w_cond2[d * 3 + 2], bb2 = b_cond2[d];
  const float2* H0 = h0f + (size_t)d * 4097;
  float gr[9], gi[9];
#pragma unroll
  for (int j = 0; j < 9; ++j) {
    const int k = tid + j * 512;
    if (k <= 4096) {
      const float a = k ? re[LP(k - 1)] : 0.f;
      const float m = re[LP(k)];
      const float z = (k < 4096) ? re[LP(k + 1)] : 0.f;
      const float ha = c0 * a + c1 * m + c2 * z + bb2;
      const float2 h = H0[k];
      const float hr = h.x + ha, hi = h.y;
      gr[j] = yr[j] * hr - yi[j] * hi;
      gi[j] = yr[j] * hi + yi[j] * hr;
      if (k == 0 || k == 4096) gi[j] = 0.f;   // irfft ignores imag of bins 0, N/2
    }
  }
  __syncthreads();
#pragma unroll
  for (int j = 0; j < 9; ++j) {
    const int k = tid + j * 512;
    if (k <= 4096) { re[LP(k)] = gr[j]; im[LP(k)] = gi[j]; }
  }
  __syncthreads();

  // -------- half-size packing Zc[k] = E^[k] + i*O^[k]; store conj(Zc) bit-reversed
  float zr2[8], zi2[8];
#pragma unroll
  for (int j = 0; j < 8; ++j) {
    const int kc = tid + j * 512;
    const int mm = 4096 - kc;
    const float ga = re[LP(kc)], gb = im[LP(kc)];
    const float gc = re[LP(mm)], gd = im[LP(mm)];
    const float Er = 0.5f * (ga + gc), Ei = 0.5f * (gb - gd);
    const float Pr = 0.5f * (ga - gc), Pi = 0.5f * (gb + gd);
    const float2 w = tw[kc];                   // e^{-2pi i k/8192}; need * conj(w)
    const float Or = Pr * w.x + Pi * w.y;
    const float Oi = Pi * w.x - Pr * w.y;
    zr2[j] = Er - Oi;
    zi2[j] = -(Ei + Or);
  }
  __syncthreads();
#pragma unroll
  for (int j = 0; j < 8; ++j) {
    const int kc = tid + j * 512;
    const int p = LP(BREV12(kc));
    re[p] = zr2[j]; im[p] = zi2[j];
  }
  // stage g1 into the free upper LDS halves (hidden under inverse FFT barriers)
  for (int j = 0; j < 16; ++j) {
    const int s = tid + j * 512;
    const float v = bf2f(g1[s]);
    if (s < 4096) re[4096 + LP(s)] = v;
    else          im[4096 + LP(s - 4096)] = v;
  }
  __syncthreads();

  inv4096<512>(re, im, tw, tid);     // out[m]: e[m]=Re/M, o[m]=-Im/M, natural order

  // -------- final: y2 = irfft * conv3(g1,ws1) -> g0 (bf16)
#define G1AT(s) ((s) < 4096 ? re[4096 + LP(s)] : im[4096 + LP((s) - 4096)])
  const float invM = 1.0f / 4096.0f;
#pragma unroll
  for (int j = 0; j < 16; ++j) {
    const int s = tid + j * 512;
    const int p = LP(s >> 1);
    const float xs = ((s & 1) ? -im[p] : re[p]) * invM;
    const float gm = s ? G1AT(s - 1) : 0.f;
    const float gcv = G1AT(s);
    const float gp = (s < 8191) ? G1AT(s + 1) : 0.f;
    const float s2v = t10 * gm + t11 * gcv + t12 * gp + bs1;
    g0[s] = f2bf(xs * s2v);
  }
#undef G1AT
}

// ---------------------------------------------------------------- y2 rows (768 x 8192) -> y2b (8192 x 768) bf16
__global__ __launch_bounds__(256) void y2t(const u16* __restrict__ y2rows, u16* __restrict__ y2b) {
  __shared__ u16 T[64][65];
  const int d0 = blockIdx.x * 64, s0 = blockIdx.y * 64;
  const int c = threadIdx.x & 63, r0 = threadIdx.x >> 6;
#pragma unroll
  for (int i = 0; i < 16; ++i) {
    const int r = r0 + i * 4;
    T[r][c] = y2rows[(size_t)(d0 + r) * 8192 + s0 + c];
  }
  __syncthreads();
#pragma unroll
  for (int i = 0; i < 16; ++i) {
    const int r = r0 + i * 4;
    y2b[(size_t)(s0 + r) * 768 + d0 + c] = T[c][r];
  }
}

// ---------------------------------------------------------------- launch
extern "C" void kernel_launch(void* const* d_in, const int* in_sizes, int n_in,
                              void* d_out, int out_size, void* d_ws, size_t ws_size,
                              hipStream_t stream) {
  (void)in_sizes; (void)n_in; (void)out_size; (void)ws_size;
  const float* x       = (const float*)d_in[0];
  const float* w_in    = (const float*)d_in[1];
  const float* b_in    = (const float*)d_in[2];
  const float* w_short = (const float*)d_in[3];
  const float* b_short = (const float*)d_in[4];
  const float* w_cond1 = (const float*)d_in[5];
  const float* b_cond1 = (const float*)d_in[6];
  const float* w_cond2 = (const float*)d_in[7];
  const float* b_cond2 = (const float*)d_in[8];
  const float* h0      = (const float*)d_in[9];
  const float* w_out   = (const float*)d_in[10];
  const float* b_out   = (const float*)d_in[11];

  float* ws = (float*)d_ws;
  float2* tw     = (float2*)ws;                          // [0, 16384)
  float2* h0f    = (float2*)(ws + 16384);                // [16384, 6309376)
  u16*    xb     = (u16*)(ws + 6309376);                 // [6309376, 9455104)
  u16*    w_inb  = (u16*)(ws + 9455104);                 // [9455104, 10339840)
  u16*    w_outb = (u16*)(ws + 10339840);                // [10339840, 10634752)
  u16*    x3Tb   = (u16*)(ws + 10634752);                // [10634752, 20071936)
  float*  h0T    = (float*)(ws + 6309376);               // transient, dead before xb.. written
  u16*    y2b    = x3Tb + 6291456;                       // aliases g1/g2 after fused_fft

  twfill<<<32, 256, 0, stream>>>(tw);
  transp<<<dim3(12, 128), 256, 0, stream>>>(h0, h0T);
  fft_h0_k<<<768, 512, 0, stream>>>(h0T, tw, h0f);
  cvt_bf16<<<864, 256, 0, stream>>>(w_in, w_inb, 221184);
  cvt_bf16<<<288, 256, 0, stream>>>(w_out, w_outb, 73728);

  for (int b = 0; b < 4; ++b) {
    cvt_bf16<<<3072, 256, 0, stream>>>(x + (size_t)b * 6291456, xb, 786432);
    gemm_bt<1><<<dim3(64, 18), 256, 0, stream>>>(w_inb, xb, b_in, x3Tb, 8192, 768);
    fused_fft<<<768, 512, 0, stream>>>(x3Tb, tw, h0f,
                                       w_short, b_short, w_cond1, b_cond1, w_cond2, b_cond2);
    y2t<<<dim3(12, 128), 256, 0, stream>>>(x3Tb, y2b);
    gemm_bt<0><<<dim3(6, 64), 256, 0, stream>>>(y2b, w_outb, b_out,
                                                (float*)d_out + (size_t)b * 6291456, 768, 768);
  }
}

// Round 8
// 735.241 us; speedup vs baseline: 4.4423x; 1.0189x over previous
//
#include <hip/hip_runtime.h>
#include <math.h>

// B=4, S=8192, D=768, W=3D=2304
// ws (floats): tw f32x2[8192]            [0       .. 16384)
//              h0f f32x2[768*4097]       [16384   .. 6309376)
//              xb   bf16 6291456 u16     [6309376 .. 9455104)
//              w_inb bf16 1769472 u16    [9455104 .. 10339840)
//              w_outb bf16 589824 u16    [10339840.. 10634752)
//              x3Tb bf16 18874368 u16    [10634752.. 20071936)   total 80.3 MB
// h0T (fp32, transient) aliases xb.. regions before they're written.
// y2b (bf16) aliases x3Tb's g1/g2 rows after fused_fft.

typedef unsigned short u16;
typedef short s16x8 __attribute__((ext_vector_type(8)));
typedef float f32x4 __attribute__((ext_vector_type(4)));
typedef u16 u16x8 __attribute__((ext_vector_type(8)));

// float2-element LDS swizzle: fold addr bits [7:4] AND [11:8] into the 16
// bank-pair index. Bijective involution (only bits [3:0] change), range-
// preserving on aligned 16-element blocks. Hand-verified 4 lanes/bank-pair
// (the b64 minimum) for every butterfly stride and the BREV scatters.
#define LPZ(i) ((i) ^ (((i) >> 4) & 15) ^ (((i) >> 8) & 15))
#define BREV13(k) ((int)(__brev((unsigned)(k)) >> 19))
#define BREV12(k) ((int)(__brev((unsigned)(k)) >> 20))
#define CMUL(rr, ri, xr, xi, wr, wi) { rr = (xr)*(wr) - (xi)*(wi); ri = (xr)*(wi) + (xi)*(wr); }

__device__ __forceinline__ u16 f2bf(float f) {
  unsigned u = __float_as_uint(f);
  u = (u + 0x7FFFu + ((u >> 16) & 1u)) >> 16;
  return (u16)u;
}
__device__ __forceinline__ float bf2f(u16 u) { return __uint_as_float(((unsigned)u) << 16); }

__device__ __forceinline__ void glds16(const void* g, void* l) {
  __builtin_amdgcn_global_load_lds((const __attribute__((address_space(1))) unsigned*)g,
                                   (__attribute__((address_space(3))) unsigned*)l, 16, 0, 0);
}

// ---------------------------------------------------------------- float -> bf16
__global__ __launch_bounds__(256) void cvt_bf16(const float* __restrict__ in,
                                                u16* __restrict__ out, int n8) {
  const int i = blockIdx.x * 256 + threadIdx.x;
  if (i < n8) {
    const float4 a = ((const float4*)in)[i * 2];
    const float4 b = ((const float4*)in)[i * 2 + 1];
    u16x8 r;
    r[0] = f2bf(a.x); r[1] = f2bf(a.y); r[2] = f2bf(a.z); r[3] = f2bf(a.w);
    r[4] = f2bf(b.x); r[5] = f2bf(b.y); r[6] = f2bf(b.z); r[7] = f2bf(b.w);
    ((u16x8*)out)[i] = r;
  }
}

// ---------------------------------------------------------------- MFMA GEMM
template <int BIAS_M>
__global__ __launch_bounds__(256) void gemm_bt(const u16* __restrict__ A,
                                               const u16* __restrict__ B,
                                               const float* __restrict__ bias,
                                               void* __restrict__ Cout,
                                               int N, int K) {
  __shared__ __align__(16) u16 As[4096];
  __shared__ __align__(16) u16 Bs[4096];
  const int tid = threadIdx.x;
  const int w = tid >> 6, l = tid & 63;
  const int m0 = blockIdx.y * 128, n0 = blockIdx.x * 128;
  const int wr = w >> 1, wc = w & 1;
  const int lr = l & 15, kc = l >> 4;

  const int p0 = w * 64 + l;
  const int p1 = p0 + 256;
  const int sl0 = (p0 & 7) ^ ((p0 >> 3) & 7);
  const int sl1 = (p1 & 7) ^ ((p1 >> 3) & 7);
  const int r0 = ((p0 >> 3) << 1) | (sl0 >> 2), ka = (sl0 & 3) << 3;
  const int r1 = ((p1 >> 3) << 1) | (sl1 >> 2), kb = (sl1 & 3) << 3;
  const u16* gA0 = A + (size_t)(m0 + r0) * K + ka;
  const u16* gA1 = A + (size_t)(m0 + r1) * K + kb;
  const u16* gB0 = B + (size_t)(n0 + r0) * K + ka;
  const u16* gB1 = B + (size_t)(n0 + r1) * K + kb;
  u16* lA0 = &As[(size_t)w * 512];
  u16* lA1 = &As[(size_t)(4 + w) * 512];
  u16* lB0 = &Bs[(size_t)w * 512];
  u16* lB1 = &Bs[(size_t)(4 + w) * 512];

  f32x4 acc[4][4] = {};

  for (int k0 = 0; k0 < K; k0 += 32) {
    glds16(gA0 + k0, lA0);
    glds16(gA1 + k0, lA1);
    glds16(gB0 + k0, lB0);
    glds16(gB1 + k0, lB1);
    __syncthreads();
    s16x8 af[4], bfr[4];
#pragma unroll
    for (int mi = 0; mi < 4; ++mi) {
      const int row = wr * 64 + mi * 16 + lr;
      const int slot = (((lr & 1) << 2) | kc) ^ ((lr >> 1) & 7);
      af[mi] = *(const s16x8*)&As[(row >> 1) * 64 + slot * 8];
    }
#pragma unroll
    for (int ni = 0; ni < 4; ++ni) {
      const int row = wc * 64 + ni * 16 + lr;
      const int slot = (((lr & 1) << 2) | kc) ^ ((lr >> 1) & 7);
      bfr[ni] = *(const s16x8*)&Bs[(row >> 1) * 64 + slot * 8];
    }
#pragma unroll
    for (int mi = 0; mi < 4; ++mi)
#pragma unroll
      for (int ni = 0; ni < 4; ++ni)
        acc[mi][ni] = __builtin_amdgcn_mfma_f32_16x16x32_bf16(af[mi], bfr[ni], acc[mi][ni], 0, 0, 0);
    __syncthreads();
  }

  const int rbase = m0 + wr * 64 + (kc << 2);
  const int cbase = n0 + wc * 64 + lr;
#pragma unroll
  for (int mi = 0; mi < 4; ++mi)
#pragma unroll
    for (int j = 0; j < 4; ++j) {
      const int row = rbase + mi * 16 + j;
      const float bm = BIAS_M ? bias[row] : 0.f;
#pragma unroll
      for (int ni = 0; ni < 4; ++ni) {
        const int col = cbase + ni * 16;
        const float v = acc[mi][ni][j] + (BIAS_M ? bm : bias[col]);
        if (BIAS_M) ((u16*)Cout)[(size_t)row * N + col] = f2bf(v);
        else        ((float*)Cout)[(size_t)row * N + col] = v;
      }
    }
}

// ---------------------------------------------------------------- twiddles exp(-2pi i k/8192), k<8192
__global__ void twfill(float2* __restrict__ tw) {
  const int k = blockIdx.x * 256 + threadIdx.x;
  if (k < 8192) {
    const double t = -2.0 * 3.14159265358979323846 * (double)k / 8192.0;
    tw[k] = make_float2((float)cos(t), (float)sin(t));
  }
}

// ---------------------------------------------------------------- h0 (8192 x 768) -> h0T (768 x 8192) fp32
__global__ __launch_bounds__(256) void transp(const float* __restrict__ in, float* __restrict__ out) {
  __shared__ float T[64][65];
  const int d0 = blockIdx.x * 64, s0 = blockIdx.y * 64;
  const int c = threadIdx.x & 63, r0 = threadIdx.x >> 6;
#pragma unroll
  for (int i = 0; i < 16; ++i) {
    const int r = r0 + i * 4;
    T[r][c] = in[(size_t)(s0 + r) * 768 + d0 + c];
  }
  __syncthreads();
#pragma unroll
  for (int i = 0; i < 16; ++i) {
    const int r = r0 + i * 4;
    out[(size_t)(d0 + r) * 8192 + s0 + c] = T[c][r];
  }
}

// ---------------------------------------------------------------- forward 8192 FFT: 6 radix-4 + 1 radix-2
// float2 LDS storage. Output layout = 13-bit bit-reversal.
template <int NT>
__device__ __forceinline__ void fwd8192(float2* z, const float2* __restrict__ tw, int tid) {
  for (int s = 13; s >= 3; s -= 2) {
    const int h = 1 << (s - 2);
    const int e = 13 - s;
#pragma unroll 2
    for (int t = 0; t < 2048 / NT; ++t) {
      const int g = tid + t * NT;
      const int b = g >> (s - 2);
      const int j = g & (h - 1);
      const int base = (b << s) | j;
      const int p0 = LPZ(base), p1 = LPZ(base + h), p2 = LPZ(base + 2 * h), p3 = LPZ(base + 3 * h);
      const float2 A = z[p0], Bv = z[p1], C = z[p2], D = z[p3];
      const float2 w1 = tw[j << e];
      const float2 w2 = tw[(2 * j) << e];
      const float2 w3 = tw[(3 * j) << e];
      const float apr = A.x + C.x, api = A.y + C.y, amr = A.x - C.x, ami = A.y - C.y;
      const float bpr = Bv.x + D.x, bpi = Bv.y + D.y, bmr = Bv.x - D.x, bmi = Bv.y - D.y;
      z[p0] = make_float2(apr + bpr, api + bpi);
      const float x1r = apr - bpr, x1i = api - bpi;
      float2 o1; CMUL(o1.x, o1.y, x1r, x1i, w2.x, w2.y); z[p1] = o1;
      const float x2r = amr + bmi, x2i = ami - bmr;      // (a-c) - i(b-d)
      float2 o2; CMUL(o2.x, o2.y, x2r, x2i, w1.x, w1.y); z[p2] = o2;
      const float x3r = amr - bmi, x3i = ami + bmr;      // (a-c) + i(b-d)
      float2 o3; CMUL(o3.x, o3.y, x3r, x3i, w3.x, w3.y); z[p3] = o3;
    }
    __syncthreads();
  }
  // final radix-2, stride 1, twiddle 1
#pragma unroll 4
  for (int t = 0; t < 4096 / NT; ++t) {
    const int g = tid + t * NT;
    const int p = LPZ(2 * g), q = LPZ(2 * g + 1);
    const float2 U = z[p], V = z[q];
    z[p] = make_float2(U.x + V.x, U.y + V.y);
    z[q] = make_float2(U.x - V.x, U.y - V.y);
  }
  __syncthreads();
}

// ---------------------------------------------------------------- inverse-core 4096 FFT (forward twiddles; caller conjugates)
// 6 pure radix-4 DIT stages; input at 12-bit bit-reversed slots, output natural.
template <int NT>
__device__ __forceinline__ void inv4096(float2* z, const float2* __restrict__ tw, int tid) {
  for (int s = 1; s <= 11; s += 2) {
    const int h = 1 << (s - 1);
    const int e = 12 - s;
#pragma unroll 2
    for (int t = 0; t < 1024 / NT; ++t) {
      const int g = tid + t * NT;
      const int b = g >> (s - 1);
      const int j = g & (h - 1);
      const int base = (b << (s + 1)) | j;
      const int p0 = LPZ(base), p1 = LPZ(base + h), p2 = LPZ(base + 2 * h), p3 = LPZ(base + 3 * h);
      const float2 A = z[p0], Bv = z[p1], C = z[p2], D = z[p3];
      const float2 w1 = tw[j << e];
      const float2 w2 = tw[(2 * j) << e];
      float vbr, vbi, vdr, vdi;
      CMUL(vbr, vbi, Bv.x, Bv.y, w2.x, w2.y);
      CMUL(vdr, vdi, D.x, D.y, w2.x, w2.y);
      const float a1r = A.x + vbr, a1i = A.y + vbi;
      const float b1r = A.x - vbr, b1i = A.y - vbi;
      const float c1r = C.x + vdr, c1i = C.y + vdi;
      const float d1r = C.x - vdr, d1i = C.y - vdi;
      float t1r, t1i, ur, ui;
      CMUL(t1r, t1i, c1r, c1i, w1.x, w1.y);
      CMUL(ur, ui, d1r, d1i, w1.y, -w1.x);               // x * (-i*w1)
      z[p0] = make_float2(a1r + t1r, a1i + t1i);
      z[p2] = make_float2(a1r - t1r, a1i - t1i);
      z[p1] = make_float2(b1r + ur, b1i + ui);
      z[p3] = make_float2(b1r - ur, b1i - ui);
    }
    __syncthreads();
  }
}

// ---------------------------------------------------------------- h0f[d,k] = rfft(h0T row d) (fp32), 512 thr
__global__ __launch_bounds__(512, 2) void fft_h0_k(const float* __restrict__ h0T,
                                                   const float2* __restrict__ tw,
                                                   float2* __restrict__ h0f) {
  __shared__ float2 z[8192];
  const int d = blockIdx.x, tid = threadIdx.x;
  const float* src = h0T + (size_t)d * 8192;
  for (int s = tid; s < 8192; s += 512) z[LPZ(s)] = make_float2(src[s], 0.f);
  __syncthreads();
  fwd8192<512>(z, tw, tid);
  for (int k = tid; k <= 4096; k += 512) {
    h0f[(size_t)d * 4097 + k] = z[LPZ(BREV13(k))];
  }
}

// ---------------------------------------------------------------- fused per-(b,d) row pipeline, 512 thr
__global__ __launch_bounds__(512, 2) void fused_fft(u16* __restrict__ x3T,
                                                    const float2* __restrict__ tw,
                                                    const float2* __restrict__ h0f,
                                                    const float* __restrict__ w_short,
                                                    const float* __restrict__ b_short,
                                                    const float* __restrict__ w_cond1,
                                                    const float* __restrict__ b_cond1,
                                                    const float* __restrict__ w_cond2,
                                                    const float* __restrict__ b_cond2) {
  __shared__ float2 z[8192];
  const int d = blockIdx.x, tid = threadIdx.x;
  u16* g0 = x3T + (size_t)d * 8192;
  const u16* g1 = x3T + (size_t)(768 + d) * 8192;
  const u16* g2 = x3T + (size_t)(1536 + d) * 8192;

  const float q0 = w_cond1[d * 3], q1 = w_cond1[d * 3 + 1], q2 = w_cond1[d * 3 + 2], bc1 = b_cond1[d];
  const float t00 = w_short[d * 3], t01 = w_short[d * 3 + 1], t02 = w_short[d * 3 + 2], bs0 = b_short[d];
  const float t10 = w_short[(768 + d) * 3], t11 = w_short[(768 + d) * 3 + 1], t12 = w_short[(768 + d) * 3 + 2], bs1 = b_short[768 + d];
  const float t20 = w_short[(1536 + d) * 3], t21 = w_short[(1536 + d) * 3 + 1], t22 = w_short[(1536 + d) * 3 + 2], bs2 = b_short[1536 + d];

  // -------- conv phase: z = {g0, g2}; then z = hc + i*y
  for (int j = 0; j < 16; ++j) { const int s = tid + j * 512; z[LPZ(s)] = make_float2(bf2f(g0[s]), bf2f(g2[s])); }
  __syncthreads();
  float ty[16], th[16];
#pragma unroll
  for (int j = 0; j < 16; ++j) {
    const int s = tid + j * 512;
    const float2 vm = s ? z[LPZ(s - 1)] : make_float2(0.f, 0.f);
    const float2 v  = z[LPZ(s)];
    const float2 vp = (s < 8191) ? z[LPZ(s + 1)] : make_float2(0.f, 0.f);
    const float s1v = t00 * vm.x + t01 * v.x + t02 * vp.x + bs0;
    const float vvv = t20 * vm.y + t21 * v.y + t22 * vp.y + bs2;
    ty[j] = s1v * vvv;
    th[j] = q0 * vm.y + q1 * v.y + q2 * vp.y + bc1;
  }
  __syncthreads();
#pragma unroll
  for (int j = 0; j < 16; ++j) { const int s = tid + j * 512; z[LPZ(s)] = make_float2(th[j], ty[j]); }
  __syncthreads();

  fwd8192<512>(z, tw, tid);          // Z = FFT(hc + i*y), bit-reversed layout

  // -------- two-for-one unpack; hm = |Hc|, Y kept in regs
  float hm[9], yr[9], yi[9];
#pragma unroll
  for (int j = 0; j < 9; ++j) {
    const int k = tid + j * 512;
    if (k <= 4096) {
      const float2 Zk = z[LPZ(BREV13(k))];
      const float2 Zm = z[LPZ(BREV13((8192 - k) & 8191))];
      const float hcr = 0.5f * (Zk.x + Zm.x), hci = 0.5f * (Zk.y - Zm.y);
      hm[j] = sqrtf(hcr * hcr + hci * hci);
      yr[j] = 0.5f * (Zk.y + Zm.y);
      yi[j] = 0.5f * (Zm.x - Zk.x);
    }
  }
  __syncthreads();
  float* hbuf = (float*)z;           // linear float scratch [0,4097)
#pragma unroll
  for (int j = 0; j < 9; ++j) { const int k = tid + j * 512; if (k <= 4096) hbuf[k] = hm[j]; }
  __syncthreads();

  // -------- h_adapt + G = Y * (h0f + ha)
  const float c0 = w_cond2[d * 3], c1 = w_cond2[d * 3 + 1], c2 = w_cond2[d * 3 + 2], bb2 = b_cond2[d];
  const float2* H0 = h0f + (size_t)d * 4097;
  float gr[9], gi[9];
#pragma unroll
  for (int j = 0; j < 9; ++j) {
    const int k = tid + j * 512;
    if (k <= 4096) {
      const float a = k ? hbuf[k - 1] : 0.f;
      const float m = hbuf[k];
      const float zn = (k < 4096) ? hbuf[k + 1] : 0.f;
      const float ha = c0 * a + c1 * m + c2 * zn + bb2;
      const float2 h = H0[k];
      const float hr = h.x + ha, hi = h.y;
      gr[j] = yr[j] * hr - yi[j] * hi;
      gi[j] = yr[j] * hi + yi[j] * hr;
      if (k == 0 || k == 4096) gi[j] = 0.f;   // irfft ignores imag of bins 0, N/2
    }
  }
  __syncthreads();
#pragma unroll
  for (int j = 0; j < 9; ++j) {
    const int k = tid + j * 512;
    if (k <= 4096) z[LPZ(k)] = make_float2(gr[j], gi[j]);
  }
  __syncthreads();

  // -------- half-size packing Zc[k] = E^[k] + i*O^[k]; store conj(Zc) bit-reversed
  float zr2[8], zi2[8];
#pragma unroll
  for (int j = 0; j < 8; ++j) {
    const int kc = tid + j * 512;
    const float2 Ga = z[LPZ(kc)];
    const float2 Gb = z[LPZ(4096 - kc)];
    const float Er = 0.5f * (Ga.x + Gb.x), Ei = 0.5f * (Ga.y - Gb.y);
    const float Pr = 0.5f * (Ga.x - Gb.x), Pi = 0.5f * (Ga.y + Gb.y);
    const float2 w = tw[kc];                   // e^{-2pi i k/8192}; need * conj(w)
    const float Or = Pr * w.x + Pi * w.y;
    const float Oi = Pi * w.x - Pr * w.y;
    zr2[j] = Er - Oi;
    zi2[j] = -(Ei + Or);
  }
  __syncthreads();
#pragma unroll
  for (int j = 0; j < 8; ++j) {
    const int kc = tid + j * 512;
    z[LPZ(BREV12(kc))] = make_float2(zr2[j], zi2[j]);
  }
  // stage g1 into the free upper LDS half (linear floats; hidden under inv FFT)
  float* g1f = (float*)(z + 4096);
  for (int j = 0; j < 16; ++j) {
    const int s = tid + j * 512;
    g1f[s] = bf2f(g1[s]);
  }
  __syncthreads();

  inv4096<512>(z, tw, tid);          // out[m]: e[m]=Re/M, o[m]=-Im/M, natural order

  // -------- final: y2 = irfft * conv3(g1,ws1) -> g0 (bf16)
  const float invM = 1.0f / 4096.0f;
#pragma unroll
  for (int j = 0; j < 16; ++j) {
    const int s = tid + j * 512;
    const float2 v = z[LPZ(s >> 1)];
    const float xs = ((s & 1) ? -v.y : v.x) * invM;
    const float gm = s ? g1f[s - 1] : 0.f;
    const float gcv = g1f[s];
    const float gp = (s < 8191) ? g1f[s + 1] : 0.f;
    const float s2v = t10 * gm + t11 * gcv + t12 * gp + bs1;
    g0[s] = f2bf(xs * s2v);
  }
}

// ---------------------------------------------------------------- y2 rows (768 x 8192) -> y2b (8192 x 768) bf16
__global__ __launch_bounds__(256) void y2t(const u16* __restrict__ y2rows, u16* __restrict__ y2b) {
  __shared__ u16 T[64][65];
  const int d0 = blockIdx.x * 64, s0 = blockIdx.y * 64;
  const int c = threadIdx.x & 63, r0 = threadIdx.x >> 6;
#pragma unroll
  for (int i = 0; i < 16; ++i) {
    const int r = r0 + i * 4;
    T[r][c] = y2rows[(size_t)(d0 + r) * 8192 + s0 + c];
  }
  __syncthreads();
#pragma unroll
  for (int i = 0; i < 16; ++i) {
    const int r = r0 + i * 4;
    y2b[(size_t)(s0 + r) * 768 + d0 + c] = T[c][r];
  }
}

// ---------------------------------------------------------------- launch
extern "C" void kernel_launch(void* const* d_in, const int* in_sizes, int n_in,
                              void* d_out, int out_size, void* d_ws, size_t ws_size,
                              hipStream_t stream) {
  (void)in_sizes; (void)n_in; (void)out_size; (void)ws_size;
  const float* x       = (const float*)d_in[0];
  const float* w_in    = (const float*)d_in[1];
  const float* b_in    = (const float*)d_in[2];
  const float* w_short = (const float*)d_in[3];
  const float* b_short = (const float*)d_in[4];
  const float* w_cond1 = (const float*)d_in[5];
  const float* b_cond1 = (const float*)d_in[6];
  const float* w_cond2 = (const float*)d_in[7];
  const float* b_cond2 = (const float*)d_in[8];
  const float* h0      = (const float*)d_in[9];
  const float* w_out   = (const float*)d_in[10];
  const float* b_out   = (const float*)d_in[11];

  float* ws = (float*)d_ws;
  float2* tw     = (float2*)ws;                          // [0, 16384)
  float2* h0f    = (float2*)(ws + 16384);                // [16384, 6309376)
  u16*    xb     = (u16*)(ws + 6309376);                 // [6309376, 9455104)
  u16*    w_inb  = (u16*)(ws + 9455104);                 // [9455104, 10339840)
  u16*    w_outb = (u16*)(ws + 10339840);                // [10339840, 10634752)
  u16*    x3Tb   = (u16*)(ws + 10634752);                // [10634752, 20071936)
  float*  h0T    = (float*)(ws + 6309376);               // transient, dead before xb.. written
  u16*    y2b    = x3Tb + 6291456;                       // aliases g1/g2 after fused_fft

  twfill<<<32, 256, 0, stream>>>(tw);
  transp<<<dim3(12, 128), 256, 0, stream>>>(h0, h0T);
  fft_h0_k<<<768, 512, 0, stream>>>(h0T, tw, h0f);
  cvt_bf16<<<864, 256, 0, stream>>>(w_in, w_inb, 221184);
  cvt_bf16<<<288, 256, 0, stream>>>(w_out, w_outb, 73728);

  for (int b = 0; b < 4; ++b) {
    cvt_bf16<<<3072, 256, 0, stream>>>(x + (size_t)b * 6291456, xb, 786432);
    gemm_bt<1><<<dim3(64, 18), 256, 0, stream>>>(w_inb, xb, b_in, x3Tb, 8192, 768);
    fused_fft<<<768, 512, 0, stream>>>(x3Tb, tw, h0f,
                                       w_short, b_short, w_cond1, b_cond1, w_cond2, b_cond2);
    y2t<<<dim3(12, 128), 256, 0, stream>>>(x3Tb, y2b);
    gemm_bt<0><<<dim3(6, 64), 256, 0, stream>>>(y2b, w_outb, b_out,
                                                (float*)d_out + (size_t)b * 6291456, 768, 768);
  }
}

// Round 9
// 640.012 us; speedup vs baseline: 5.1033x; 1.1488x over previous
//
#include <hip/hip_runtime.h>
#include <math.h>

// B=4, S=8192, D=768, W=3D=2304
// ws (floats): tw f32x2[8192]            [0       .. 16384)
//              h0f f32x2[768*4097]       [16384   .. 6309376)
//              xb   bf16 6291456 u16     [6309376 .. 9455104)
//              w_inb bf16 1769472 u16    [9455104 .. 10339840)
//              w_outb bf16 589824 u16    [10339840.. 10634752)
//              x3Tb bf16 18874368 u16    [10634752.. 20071936)   total 80.3 MB
// h0T (fp32, transient) aliases xb.. regions before they're written.
// y2b (bf16) aliases x3Tb's g1/g2 rows after fused_fft.

typedef unsigned short u16;
typedef short s16x8 __attribute__((ext_vector_type(8)));
typedef float f32x4 __attribute__((ext_vector_type(4)));
typedef u16 u16x8 __attribute__((ext_vector_type(8)));

// float2-element LDS swizzle: fold addr bits [7:4] and [11:8] into the 16
// bank-pair index. Bijective involution, range-preserving (verified R8:
// conflicts 9.6e6 -> 3.2e6).
#define LPZ(i) ((i) ^ (((i) >> 4) & 15) ^ (((i) >> 8) & 15))
#define BREV13(k) ((int)(__brev((unsigned)(k)) >> 19))
#define BREV12(k) ((int)(__brev((unsigned)(k)) >> 20))
#define CMUL(rr, ri, xr, xi, wr, wi) { rr = (xr)*(wr) - (xi)*(wi); ri = (xr)*(wi) + (xi)*(wr); }

__device__ __forceinline__ u16 f2bf(float f) {
  unsigned u = __float_as_uint(f);
  u = (u + 0x7FFFu + ((u >> 16) & 1u)) >> 16;
  return (u16)u;
}
__device__ __forceinline__ float bf2f(u16 u) { return __uint_as_float(((unsigned)u) << 16); }

__device__ __forceinline__ void glds16(const void* g, void* l) {
  __builtin_amdgcn_global_load_lds((const __attribute__((address_space(1))) unsigned*)g,
                                   (__attribute__((address_space(3))) unsigned*)l, 16, 0, 0);
}

// ---------------------------------------------------------------- float -> bf16
__global__ __launch_bounds__(256) void cvt_bf16(const float* __restrict__ in,
                                                u16* __restrict__ out, int n8) {
  const int i = blockIdx.x * 256 + threadIdx.x;
  if (i < n8) {
    const float4 a = ((const float4*)in)[i * 2];
    const float4 b = ((const float4*)in)[i * 2 + 1];
    u16x8 r;
    r[0] = f2bf(a.x); r[1] = f2bf(a.y); r[2] = f2bf(a.z); r[3] = f2bf(a.w);
    r[4] = f2bf(b.x); r[5] = f2bf(b.y); r[6] = f2bf(b.z); r[7] = f2bf(b.w);
    ((u16x8*)out)[i] = r;
  }
}

// ---------------------------------------------------------------- MFMA GEMM
template <int BIAS_M>
__global__ __launch_bounds__(256) void gemm_bt(const u16* __restrict__ A,
                                               const u16* __restrict__ B,
                                               const float* __restrict__ bias,
                                               void* __restrict__ Cout,
                                               int N, int K) {
  __shared__ __align__(16) u16 As[4096];
  __shared__ __align__(16) u16 Bs[4096];
  const int tid = threadIdx.x;
  const int w = tid >> 6, l = tid & 63;
  const int m0 = blockIdx.y * 128, n0 = blockIdx.x * 128;
  const int wr = w >> 1, wc = w & 1;
  const int lr = l & 15, kc = l >> 4;

  const int p0 = w * 64 + l;
  const int p1 = p0 + 256;
  const int sl0 = (p0 & 7) ^ ((p0 >> 3) & 7);
  const int sl1 = (p1 & 7) ^ ((p1 >> 3) & 7);
  const int r0 = ((p0 >> 3) << 1) | (sl0 >> 2), ka = (sl0 & 3) << 3;
  const int r1 = ((p1 >> 3) << 1) | (sl1 >> 2), kb = (sl1 & 3) << 3;
  const u16* gA0 = A + (size_t)(m0 + r0) * K + ka;
  const u16* gA1 = A + (size_t)(m0 + r1) * K + kb;
  const u16* gB0 = B + (size_t)(n0 + r0) * K + ka;
  const u16* gB1 = B + (size_t)(n0 + r1) * K + kb;
  u16* lA0 = &As[(size_t)w * 512];
  u16* lA1 = &As[(size_t)(4 + w) * 512];
  u16* lB0 = &Bs[(size_t)w * 512];
  u16* lB1 = &Bs[(size_t)(4 + w) * 512];

  f32x4 acc[4][4] = {};

  for (int k0 = 0; k0 < K; k0 += 32) {
    glds16(gA0 + k0, lA0);
    glds16(gA1 + k0, lA1);
    glds16(gB0 + k0, lB0);
    glds16(gB1 + k0, lB1);
    __syncthreads();
    s16x8 af[4], bfr[4];
#pragma unroll
    for (int mi = 0; mi < 4; ++mi) {
      const int row = wr * 64 + mi * 16 + lr;
      const int slot = (((lr & 1) << 2) | kc) ^ ((lr >> 1) & 7);
      af[mi] = *(const s16x8*)&As[(row >> 1) * 64 + slot * 8];
    }
#pragma unroll
    for (int ni = 0; ni < 4; ++ni) {
      const int row = wc * 64 + ni * 16 + lr;
      const int slot = (((lr & 1) << 2) | kc) ^ ((lr >> 1) & 7);
      bfr[ni] = *(const s16x8*)&Bs[(row >> 1) * 64 + slot * 8];
    }
#pragma unroll
    for (int mi = 0; mi < 4; ++mi)
#pragma unroll
      for (int ni = 0; ni < 4; ++ni)
        acc[mi][ni] = __builtin_amdgcn_mfma_f32_16x16x32_bf16(af[mi], bfr[ni], acc[mi][ni], 0, 0, 0);
    __syncthreads();
  }

  const int rbase = m0 + wr * 64 + (kc << 2);
  const int cbase = n0 + wc * 64 + lr;
#pragma unroll
  for (int mi = 0; mi < 4; ++mi)
#pragma unroll
    for (int j = 0; j < 4; ++j) {
      const int row = rbase + mi * 16 + j;
      const float bm = BIAS_M ? bias[row] : 0.f;
#pragma unroll
      for (int ni = 0; ni < 4; ++ni) {
        const int col = cbase + ni * 16;
        const float v = acc[mi][ni][j] + (BIAS_M ? bm : bias[col]);
        if (BIAS_M) ((u16*)Cout)[(size_t)row * N + col] = f2bf(v);
        else        ((float*)Cout)[(size_t)row * N + col] = v;
      }
    }
}

// ---------------------------------------------------------------- twiddles exp(-2pi i k/8192), k<8192
__global__ void twfill(float2* __restrict__ tw) {
  const int k = blockIdx.x * 256 + threadIdx.x;
  if (k < 8192) {
    const double t = -2.0 * 3.14159265358979323846 * (double)k / 8192.0;
    tw[k] = make_float2((float)cos(t), (float)sin(t));
  }
}

// ---------------------------------------------------------------- h0 (8192 x 768) -> h0T (768 x 8192) fp32
__global__ __launch_bounds__(256) void transp(const float* __restrict__ in, float* __restrict__ out) {
  __shared__ float T[64][65];
  const int d0 = blockIdx.x * 64, s0 = blockIdx.y * 64;
  const int c = threadIdx.x & 63, r0 = threadIdx.x >> 6;
#pragma unroll
  for (int i = 0; i < 16; ++i) {
    const int r = r0 + i * 4;
    T[r][c] = in[(size_t)(s0 + r) * 768 + d0 + c];
  }
  __syncthreads();
#pragma unroll
  for (int i = 0; i < 16; ++i) {
    const int r = r0 + i * 4;
    out[(size_t)(d0 + r) * 8192 + s0 + c] = T[c][r];
  }
}

// ---------------------------------------------------------------- butterfly bodies (identical math to R5-R8)
__device__ __forceinline__ void dif4(float2& A, float2& B, float2& C, float2& D,
                                     float2 w1, float2 w2, float2 w3) {
  const float apr = A.x + C.x, api = A.y + C.y, amr = A.x - C.x, ami = A.y - C.y;
  const float bpr = B.x + D.x, bpi = B.y + D.y, bmr = B.x - D.x, bmi = B.y - D.y;
  const float2 o0 = make_float2(apr + bpr, api + bpi);
  const float x1r = apr - bpr, x1i = api - bpi;
  float2 o1; CMUL(o1.x, o1.y, x1r, x1i, w2.x, w2.y);
  const float x2r = amr + bmi, x2i = ami - bmr;          // (a-c) - i(b-d)
  float2 o2; CMUL(o2.x, o2.y, x2r, x2i, w1.x, w1.y);
  const float x3r = amr - bmi, x3i = ami + bmr;          // (a-c) + i(b-d)
  float2 o3; CMUL(o3.x, o3.y, x3r, x3i, w3.x, w3.y);
  A = o0; B = o1; C = o2; D = o3;
}

__device__ __forceinline__ void dit4(float2& A, float2& B, float2& C, float2& D,
                                     float2 w1, float2 w2) {
  float vbr, vbi, vdr, vdi;
  CMUL(vbr, vbi, B.x, B.y, w2.x, w2.y);
  CMUL(vdr, vdi, D.x, D.y, w2.x, w2.y);
  const float a1r = A.x + vbr, a1i = A.y + vbi;
  const float b1r = A.x - vbr, b1i = A.y - vbi;
  const float c1r = C.x + vdr, c1i = C.y + vdi;
  const float d1r = C.x - vdr, d1i = C.y - vdi;
  float t1r, t1i, ur, ui;
  CMUL(t1r, t1i, c1r, c1i, w1.x, w1.y);
  CMUL(ur, ui, d1r, d1i, w1.y, -w1.x);                   // x * (-i*w1)
  A = make_float2(a1r + t1r, a1i + t1i);
  C = make_float2(a1r - t1r, a1i - t1i);
  B = make_float2(b1r + ur,  b1i + ui);
  D = make_float2(b1r - ur,  b1i - ui);
}

// ---------------------------------------------------------------- radix-16 pass = two radix-4 layers fused in regs
// Set = {base + m*st}, m=0..15. Layer A: stage with arm stride 4*st, j_c = jp + c*st,
// twiddle exp e. Layer B: stage with arm stride st, j'' = jp, exp e+2. jp < st.
__device__ __forceinline__ void fwd_pass16(float2* z, const float2* __restrict__ tw,
                                           int base, int jp, int st, int e) {
  float2 v[16]; int idx[16];
#pragma unroll
  for (int m = 0; m < 16; ++m) { idx[m] = LPZ(base + m * st); v[m] = z[idx[m]]; }
#pragma unroll
  for (int c = 0; c < 4; ++c) {
    const int jc = jp + c * st;
    dif4(v[c], v[c + 4], v[c + 8], v[c + 12],
         tw[jc << e], tw[(2 * jc) << e], tw[(3 * jc) << e]);
  }
  const float2 u1 = tw[jp << (e + 2)];
  const float2 u2 = tw[(2 * jp) << (e + 2)];
  const float2 u3 = tw[(3 * jp) << (e + 2)];
#pragma unroll
  for (int a = 0; a < 4; ++a)
    dif4(v[4 * a], v[4 * a + 1], v[4 * a + 2], v[4 * a + 3], u1, u2, u3);
#pragma unroll
  for (int m = 0; m < 16; ++m) z[idx[m]] = v[m];
}

// DIT mirror: layer A = stage s (arm stride st, j = jp, exp e); layer B = stage s+2
// (arm stride 4*st, j'' = c*st + jp, exp e-2).
__device__ __forceinline__ void inv_pass16(float2* z, const float2* __restrict__ tw,
                                           int base, int jp, int st, int e) {
  float2 v[16]; int idx[16];
#pragma unroll
  for (int m = 0; m < 16; ++m) { idx[m] = LPZ(base + m * st); v[m] = z[idx[m]]; }
  const float2 w1 = tw[jp << e];
  const float2 w2 = tw[(2 * jp) << e];
#pragma unroll
  for (int a = 0; a < 4; ++a)
    dit4(v[4 * a], v[4 * a + 1], v[4 * a + 2], v[4 * a + 3], w1, w2);
#pragma unroll
  for (int c = 0; c < 4; ++c) {
    const int jpp = c * st + jp;
    dit4(v[c], v[c + 4], v[c + 8], v[c + 12],
         tw[jpp << (e - 2)], tw[(2 * jpp) << (e - 2)]);
  }
#pragma unroll
  for (int m = 0; m < 16; ++m) z[idx[m]] = v[m];
}

// ---------------------------------------------------------------- forward 8192 FFT: 3 radix-16 passes + radix-2
// Same butterflies/twiddles/order as the verified radix-4 chain (s=13,11 | 9,7 | 5,3 | 2-final);
// output layout = 13-bit bit-reversal. NT must be 512.
template <int NT>
__device__ __forceinline__ void fwd8192(float2* z, const float2* __restrict__ tw, int tid) {
  fwd_pass16(z, tw, tid, tid, 512, 0);                                    // stages 13,11
  __syncthreads();
  fwd_pass16(z, tw, ((tid >> 5) << 9) | (tid & 31), tid & 31, 32, 4);     // stages 9,7
  __syncthreads();
  fwd_pass16(z, tw, ((tid >> 1) << 5) | (tid & 1), tid & 1, 2, 8);        // stages 5,3
  __syncthreads();
#pragma unroll
  for (int t = 0; t < 8; ++t) {                                           // final radix-2
    const int g = tid + t * 512;
    const int p = LPZ(2 * g), q = LPZ(2 * g + 1);
    const float2 U = z[p], V = z[q];
    z[p] = make_float2(U.x + V.x, U.y + V.y);
    z[q] = make_float2(U.x - V.x, U.y - V.y);
  }
  __syncthreads();
}

// ---------------------------------------------------------------- inverse-core 4096 FFT: 3 radix-16 passes
// (forward twiddles; caller conjugates). Input 12-bit bit-reversed, output natural.
template <int NT>
__device__ __forceinline__ void inv4096(float2* z, const float2* __restrict__ tw, int tid) {
  if (tid < 256) inv_pass16(z, tw, tid << 4, 0, 1, 11);                            // stages 1,3
  __syncthreads();
  if (tid < 256) inv_pass16(z, tw, ((tid >> 4) << 8) | (tid & 15), tid & 15, 16, 7); // stages 5,7
  __syncthreads();
  if (tid < 256) inv_pass16(z, tw, tid, tid, 256, 3);                              // stages 9,11
  __syncthreads();
}

// ---------------------------------------------------------------- h0f[d,k] = rfft(h0T row d) (fp32), 512 thr
__global__ __launch_bounds__(512, 2) void fft_h0_k(const float* __restrict__ h0T,
                                                   const float2* __restrict__ tw,
                                                   float2* __restrict__ h0f) {
  __shared__ float2 z[8192];
  const int d = blockIdx.x, tid = threadIdx.x;
  const float* src = h0T + (size_t)d * 8192;
  for (int s = tid; s < 8192; s += 512) z[LPZ(s)] = make_float2(src[s], 0.f);
  __syncthreads();
  fwd8192<512>(z, tw, tid);
  for (int k = tid; k <= 4096; k += 512) {
    h0f[(size_t)d * 4097 + k] = z[LPZ(BREV13(k))];
  }
}

// ---------------------------------------------------------------- fused per-(b,d) row pipeline, 512 thr
__global__ __launch_bounds__(512, 2) void fused_fft(u16* __restrict__ x3T,
                                                    const float2* __restrict__ tw,
                                                    const float2* __restrict__ h0f,
                                                    const float* __restrict__ w_short,
                                                    const float* __restrict__ b_short,
                                                    const float* __restrict__ w_cond1,
                                                    const float* __restrict__ b_cond1,
                                                    const float* __restrict__ w_cond2,
                                                    const float* __restrict__ b_cond2) {
  __shared__ float2 z[8192];
  const int d = blockIdx.x, tid = threadIdx.x;
  u16* g0 = x3T + (size_t)d * 8192;
  const u16* g1 = x3T + (size_t)(768 + d) * 8192;
  const u16* g2 = x3T + (size_t)(1536 + d) * 8192;

  const float q0 = w_cond1[d * 3], q1 = w_cond1[d * 3 + 1], q2 = w_cond1[d * 3 + 2], bc1 = b_cond1[d];
  const float t00 = w_short[d * 3], t01 = w_short[d * 3 + 1], t02 = w_short[d * 3 + 2], bs0 = b_short[d];
  const float t10 = w_short[(768 + d) * 3], t11 = w_short[(768 + d) * 3 + 1], t12 = w_short[(768 + d) * 3 + 2], bs1 = b_short[768 + d];
  const float t20 = w_short[(1536 + d) * 3], t21 = w_short[(1536 + d) * 3 + 1], t22 = w_short[(1536 + d) * 3 + 2], bs2 = b_short[1536 + d];

  // -------- conv phase: z = {g0, g2}; then z = hc + i*y
  for (int j = 0; j < 16; ++j) { const int s = tid + j * 512; z[LPZ(s)] = make_float2(bf2f(g0[s]), bf2f(g2[s])); }
  __syncthreads();
  float ty[16], th[16];
#pragma unroll
  for (int j = 0; j < 16; ++j) {
    const int s = tid + j * 512;
    const float2 vm = s ? z[LPZ(s - 1)] : make_float2(0.f, 0.f);
    const float2 v  = z[LPZ(s)];
    const float2 vp = (s < 8191) ? z[LPZ(s + 1)] : make_float2(0.f, 0.f);
    const float s1v = t00 * vm.x + t01 * v.x + t02 * vp.x + bs0;
    const float vvv = t20 * vm.y + t21 * v.y + t22 * vp.y + bs2;
    ty[j] = s1v * vvv;
    th[j] = q0 * vm.y + q1 * v.y + q2 * vp.y + bc1;
  }
  __syncthreads();
#pragma unroll
  for (int j = 0; j < 16; ++j) { const int s = tid + j * 512; z[LPZ(s)] = make_float2(th[j], ty[j]); }
  __syncthreads();

  fwd8192<512>(z, tw, tid);          // Z = FFT(hc + i*y), bit-reversed layout

  // -------- two-for-one unpack; hm = |Hc|, Y kept in regs
  float hm[9], yr[9], yi[9];
#pragma unroll
  for (int j = 0; j < 9; ++j) {
    const int k = tid + j * 512;
    if (k <= 4096) {
      const float2 Zk = z[LPZ(BREV13(k))];
      const float2 Zm = z[LPZ(BREV13((8192 - k) & 8191))];
      const float hcr = 0.5f * (Zk.x + Zm.x), hci = 0.5f * (Zk.y - Zm.y);
      hm[j] = sqrtf(hcr * hcr + hci * hci);
      yr[j] = 0.5f * (Zk.y + Zm.y);
      yi[j] = 0.5f * (Zm.x - Zk.x);
    }
  }
  __syncthreads();
  float* hbuf = (float*)z;           // linear float scratch [0,4097)
#pragma unroll
  for (int j = 0; j < 9; ++j) { const int k = tid + j * 512; if (k <= 4096) hbuf[k] = hm[j]; }
  __syncthreads();

  // -------- h_adapt + G = Y * (h0f + ha)
  const float c0 = w_cond2[d * 3], c1 = w_cond2[d * 3 + 1], c2 = w_cond2[d * 3 + 2], bb2 = b_cond2[d];
  const float2* H0 = h0f + (size_t)d * 4097;
  float gr[9], gi[9];
#pragma unroll
  for (int j = 0; j < 9; ++j) {
    const int k = tid + j * 512;
    if (k <= 4096) {
      const float a = k ? hbuf[k - 1] : 0.f;
      const float m = hbuf[k];
      const float zn = (k < 4096) ? hbuf[k + 1] : 0.f;
      const float ha = c0 * a + c1 * m + c2 * zn + bb2;
      const float2 h = H0[k];
      const float hr = h.x + ha, hi = h.y;
      gr[j] = yr[j] * hr - yi[j] * hi;
      gi[j] = yr[j] * hi + yi[j] * hr;
      if (k == 0 || k == 4096) gi[j] = 0.f;   // irfft ignores imag of bins 0, N/2
    }
  }
  __syncthreads();
#pragma unroll
  for (int j = 0; j < 9; ++j) {
    const int k = tid + j * 512;
    if (k <= 4096) z[LPZ(k)] = make_float2(gr[j], gi[j]);
  }
  __syncthreads();

  // -------- half-size packing Zc[k] = E^[k] + i*O^[k]; store conj(Zc) bit-reversed
  float zr2[8], zi2[8];
#pragma unroll
  for (int j = 0; j < 8; ++j) {
    const int kc = tid + j * 512;
    const float2 Ga = z[LPZ(kc)];
    const float2 Gb = z[LPZ(4096 - kc)];
    const float Er = 0.5f * (Ga.x + Gb.x), Ei = 0.5f * (Ga.y - Gb.y);
    const float Pr = 0.5f * (Ga.x - Gb.x), Pi = 0.5f * (Ga.y + Gb.y);
    const float2 w = tw[kc];                   // e^{-2pi i k/8192}; need * conj(w)
    const float Or = Pr * w.x + Pi * w.y;
    const float Oi = Pi * w.x - Pr * w.y;
    zr2[j] = Er - Oi;
    zi2[j] = -(Ei + Or);
  }
  __syncthreads();
#pragma unroll
  for (int j = 0; j < 8; ++j) {
    const int kc = tid + j * 512;
    z[LPZ(BREV12(kc))] = make_float2(zr2[j], zi2[j]);
  }
  // stage g1 into the free upper LDS half (linear floats; hidden under inv FFT)
  float* g1f = (float*)(z + 4096);
  for (int j = 0; j < 16; ++j) {
    const int s = tid + j * 512;
    g1f[s] = bf2f(g1[s]);
  }
  __syncthreads();

  inv4096<512>(z, tw, tid);          // out[m]: e[m]=Re/M, o[m]=-Im/M, natural order

  // -------- final: y2 = irfft * conv3(g1,ws1) -> g0 (bf16)
  const float invM = 1.0f / 4096.0f;
#pragma unroll
  for (int j = 0; j < 16; ++j) {
    const int s = tid + j * 512;
    const float2 v = z[LPZ(s >> 1)];
    const float xs = ((s & 1) ? -v.y : v.x) * invM;
    const float gm = s ? g1f[s - 1] : 0.f;
    const float gcv = g1f[s];
    const float gp = (s < 8191) ? g1f[s + 1] : 0.f;
    const float s2v = t10 * gm + t11 * gcv + t12 * gp + bs1;
    g0[s] = f2bf(xs * s2v);
  }
}

// ---------------------------------------------------------------- y2 rows (768 x 8192) -> y2b (8192 x 768) bf16
__global__ __launch_bounds__(256) void y2t(const u16* __restrict__ y2rows, u16* __restrict__ y2b) {
  __shared__ u16 T[64][65];
  const int d0 = blockIdx.x * 64, s0 = blockIdx.y * 64;
  const int c = threadIdx.x & 63, r0 = threadIdx.x >> 6;
#pragma unroll
  for (int i = 0; i < 16; ++i) {
    const int r = r0 + i * 4;
    T[r][c] = y2rows[(size_t)(d0 + r) * 8192 + s0 + c];
  }
  __syncthreads();
#pragma unroll
  for (int i = 0; i < 16; ++i) {
    const int r = r0 + i * 4;
    y2b[(size_t)(s0 + r) * 768 + d0 + c] = T[c][r];
  }
}

// ---------------------------------------------------------------- launch
extern "C" void kernel_launch(void* const* d_in, const int* in_sizes, int n_in,
                              void* d_out, int out_size, void* d_ws, size_t ws_size,
                              hipStream_t stream) {
  (void)in_sizes; (void)n_in; (void)out_size; (void)ws_size;
  const float* x       = (const float*)d_in[0];
  const float* w_in    = (const float*)d_in[1];
  const float* b_in    = (const float*)d_in[2];
  const float* w_short = (const float*)d_in[3];
  const float* b_short = (const float*)d_in[4];
  const float* w_cond1 = (const float*)d_in[5];
  const float* b_cond1 = (const float*)d_in[6];
  const float* w_cond2 = (const float*)d_in[7];
  const float* b_cond2 = (const float*)d_in[8];
  const float* h0      = (const float*)d_in[9];
  const float* w_out   = (const float*)d_in[10];
  const float* b_out   = (const float*)d_in[11];

  float* ws = (float*)d_ws;
  float2* tw     = (float2*)ws;                          // [0, 16384)
  float2* h0f    = (float2*)(ws + 16384);                // [16384, 6309376)
  u16*    xb     = (u16*)(ws + 6309376);                 // [6309376, 9455104)
  u16*    w_inb  = (u16*)(ws + 9455104);                 // [9455104, 10339840)
  u16*    w_outb = (u16*)(ws + 10339840);                // [10339840, 10634752)
  u16*    x3Tb   = (u16*)(ws + 10634752);                // [10634752, 20071936)
  float*  h0T    = (float*)(ws + 6309376);               // transient, dead before xb.. written
  u16*    y2b    = x3Tb + 6291456;                       // aliases g1/g2 after fused_fft

  twfill<<<32, 256, 0, stream>>>(tw);
  transp<<<dim3(12, 128), 256, 0, stream>>>(h0, h0T);
  fft_h0_k<<<768, 512, 0, stream>>>(h0T, tw, h0f);
  cvt_bf16<<<864, 256, 0, stream>>>(w_in, w_inb, 221184);
  cvt_bf16<<<288, 256, 0, stream>>>(w_out, w_outb, 73728);

  for (int b = 0; b < 4; ++b) {
    cvt_bf16<<<3072, 256, 0, stream>>>(x + (size_t)b * 6291456, xb, 786432);
    gemm_bt<1><<<dim3(64, 18), 256, 0, stream>>>(w_inb, xb, b_in, x3Tb, 8192, 768);
    fused_fft<<<768, 512, 0, stream>>>(x3Tb, tw, h0f,
                                       w_short, b_short, w_cond1, b_cond1, w_cond2, b_cond2);
    y2t<<<dim3(12, 128), 256, 0, stream>>>(x3Tb, y2b);
    gemm_bt<0><<<dim3(6, 64), 256, 0, stream>>>(y2b, w_outb, b_out,
                                                (float*)d_out + (size_t)b * 6291456, 768, 768);
  }
}